// Round 4
// baseline (1091.442 us; speedup 1.0000x reference)
//
#include <hip/hip_runtime.h>
#include <hip/hip_bf16.h>

#define NN 50000
#define NE 800000

typedef unsigned short u16;
typedef unsigned int   u32;

typedef __attribute__((ext_vector_type(8))) __bf16 bf16x8;
typedef __attribute__((ext_vector_type(4))) float  f32x4;

__device__ __forceinline__ float bf2f(u16 x) {
    u32 u = ((u32)x) << 16;
    return __builtin_bit_cast(float, u);
}
__device__ __forceinline__ u16 f2bf(float f) {
    u32 u = __builtin_bit_cast(u32, f);
    u32 r = (u + 0x7FFFu + ((u >> 16) & 1u)) >> 16;
    return (u16)r;
}
__device__ __forceinline__ float bflo(u32 w) { return __builtin_bit_cast(float, w << 16); }
__device__ __forceinline__ float bfhi(u32 w) { return __builtin_bit_cast(float, w & 0xffff0000u); }

// ---------------- graph preprocessing ----------------

__global__ __launch_bounds__(256) void count_k(const int* __restrict__ dst, int* __restrict__ deg, int E) {
    int e = blockIdx.x * 256 + threadIdx.x;
    if (e < E) atomicAdd(&deg[dst[e]], 1);
}

__global__ __launch_bounds__(256) void dinv_k(const int* __restrict__ deg, float* __restrict__ dinv, int n) {
    int i = blockIdx.x * 256 + threadIdx.x;
    if (i < n) dinv[i] = rsqrtf((float)deg[i] + 1.0f);
}

__global__ __launch_bounds__(256) void scan1_k(const int* __restrict__ deg, int* __restrict__ bsum, int n) {
    __shared__ int sd[256];
    int i = blockIdx.x * 256 + threadIdx.x;
    sd[threadIdx.x] = (i < n) ? deg[i] : 0;
    __syncthreads();
    for (int s = 128; s > 0; s >>= 1) {
        if (threadIdx.x < s) sd[threadIdx.x] += sd[threadIdx.x + s];
        __syncthreads();
    }
    if (threadIdx.x == 0) bsum[blockIdx.x] = sd[0];
}

__global__ __launch_bounds__(256) void scan2_k(int* __restrict__ bsum, int nb) {
    __shared__ int sd[256];
    int t = threadIdx.x;
    int v = (t < nb) ? bsum[t] : 0;
    sd[t] = v;
    __syncthreads();
    for (int off = 1; off < 256; off <<= 1) {
        int tv = (t >= off) ? sd[t - off] : 0;
        __syncthreads();
        sd[t] += tv;
        __syncthreads();
    }
    if (t < nb) bsum[t] = sd[t] - v;  // exclusive
}

__global__ __launch_bounds__(256) void scan3_k(const int* __restrict__ deg, const int* __restrict__ bofs,
                                               int* __restrict__ rs, int* __restrict__ cur, int n) {
    __shared__ int sd[256];
    int t = threadIdx.x;
    int i = blockIdx.x * 256 + t;
    int v = (i < n) ? deg[i] : 0;
    sd[t] = v;
    __syncthreads();
    for (int off = 1; off < 256; off <<= 1) {
        int tv = (t >= off) ? sd[t - off] : 0;
        __syncthreads();
        sd[t] += tv;
        __syncthreads();
    }
    int excl = sd[t] - v + bofs[blockIdx.x];
    if (i < n) { rs[i] = excl; cur[i] = excl; }
}

__global__ __launch_bounds__(256) void fill_k(const int* __restrict__ src, const int* __restrict__ dst,
                                              int* __restrict__ cur, int* __restrict__ csr, int E) {
    int e = blockIdx.x * 256 + threadIdx.x;
    if (e < E) {
        int d = dst[e];
        int pos = atomicAdd(&cur[d], 1);
        csr[pos] = src[e];
    }
}

// ---------------- x f32 -> bf16 cast ----------------

__global__ __launch_bounds__(256) void cast_k(const float* __restrict__ X, u16* __restrict__ Y, int total) {
    int idx = (blockIdx.x * 256 + threadIdx.x) * 8;
    if (idx >= total) return;
    float4 a = *(const float4*)(X + idx);
    float4 b = *(const float4*)(X + idx + 4);
    uint4 o;
    o.x = (u32)f2bf(a.x) | ((u32)f2bf(a.y) << 16);
    o.y = (u32)f2bf(a.z) | ((u32)f2bf(a.w) << 16);
    o.z = (u32)f2bf(b.x) | ((u32)f2bf(b.y) << 16);
    o.w = (u32)f2bf(b.z) | ((u32)f2bf(b.w) << 16);
    *(uint4*)(Y + idx) = o;
}

// ---------------- weight transpose+cast: W f32[K][F] -> Wt bf16[F][K] ----------------

__global__ __launch_bounds__(256) void transpose_k(const float* __restrict__ W, u16* __restrict__ Wt, int K, int F) {
    __shared__ float t[32][33];
    int k0 = blockIdx.x * 32, f0 = blockIdx.y * 32;
    int tx = threadIdx.x & 31, ty = threadIdx.x >> 5;
    for (int r = ty; r < 32; r += 8) t[r][tx] = W[(size_t)(k0 + r) * F + f0 + tx];
    __syncthreads();
    for (int r = ty; r < 32; r += 8) Wt[(size_t)(f0 + r) * K + k0 + tx] = f2bf(t[tx][r]);
}

// ---------------- XCD-chunked GCN aggregation (pull, CSR by dst) ----------------
// The gather working set (X) is replicated across the 8 per-XCD L2s by random block
// placement -> ~48% L2 miss (measured: FETCH 405MB of 850MB touched). Fix: partition
// features into 8 chunks of 32 and pin chunk c to XCD c via c = blockIdx.x % 8
// (dispatch round-robins blocks over XCDs; heuristic affects speed only, not
// correctness). Per-XCD slice = NN*64B = 3.2MB < 4MB L2 -> resident, replication -> 1.
// F=512 runs as two sequential launches (chbase 0, 8) to keep the slice <= 3.2MB.
//
// Wave layout: lane = (q, fp), q=lane>>4 = edge slot (4 edges gathered per load
// instr), fp=lane&15 = feature pair (2 bf16 via one dword). Butterfly-reduce the 4
// edge slots at the end. No LDS, no barriers, no atomics; deterministic per node.
// MODE 0: plain gather, bf16 out.             (agg1: XB -> A1)
// MODE 1: BN+ReLU per gathered value, bf16 out.   (agg2)
// MODE 2: plain gather + b3 + xres, f32 out.      (agg3, final layer)

template <int F, int MODE>
__global__ __launch_bounds__(256) void aggc_k(const u16* __restrict__ X, u16* __restrict__ Y,
                                              float* __restrict__ Yf,
                                              const float* __restrict__ dinv, const int* __restrict__ rs,
                                              const int* __restrict__ dg, const int* __restrict__ csr,
                                              const float* __restrict__ scale, const float* __restrict__ shift,
                                              const float* __restrict__ b3, const float* __restrict__ xres,
                                              int chbase) {
    const int bid  = blockIdx.x;
    const int ch   = (bid & 7) + chbase;   // chunk -> XCD pinning
    const int nb   = bid >> 3;
    const int tid  = threadIdx.x;
    const int wv   = tid >> 6;
    const int lane = tid & 63;
    const int q    = lane >> 4;            // edge slot 0..3
    const int fp   = lane & 15;            // feature pair 0..15
    const int fbase = ch * 32 + fp * 2;

    float sc0 = 0.f, sc1 = 0.f, sh0 = 0.f, sh1 = 0.f;
    if constexpr (MODE == 1) {
        sc0 = scale[fbase]; sc1 = scale[fbase + 1];
        sh0 = shift[fbase]; sh1 = shift[fbase + 1];
    }
    float bb0 = 0.f, bb1 = 0.f;
    if constexpr (MODE == 2) { bb0 = b3[fbase]; bb1 = b3[fbase + 1]; }

    const int i0 = nb * 32 + wv * 8;       // 4 waves x 8 nodes per block
    for (int n = 0; n < 8; n++) {
        const int i = i0 + n;
        if (i >= NN) break;
        const int start = rs[i], cnt = dg[i];
        const float di = dinv[i];

        float a0 = 0.f, a1 = 0.f;
        // self-loop term (slot 0 only; counted once after the butterfly reduce)
        {
            u32 v = *(const u32*)(X + (size_t)i * F + fbase);
            float x0 = bflo(v), x1 = bfhi(v);
            if constexpr (MODE == 1) {
                x0 = fmaxf(fmaf(x0, sc0, sh0), 0.f);
                x1 = fmaxf(fmaf(x1, sc1, sh1), 0.f);
            }
            if (q == 0) { a0 = x0 * di; a1 = x1 * di; }
        }

        for (int base = 0; base < cnt; base += 64) {
            const int m = min(64, cnt - base);
            int   sidx = 0;
            float sw   = 0.f;   // lanes >= m keep (row 0, weight 0): safe, zero contribution
            if (lane < m) {
                sidx = csr[start + base + lane];
                sw   = dinv[sidx];
            }
            #pragma unroll 4
            for (int j = 0; j < m; j += 4) {
                int   row = __shfl(sidx, j + q);
                float w   = __shfl(sw,   j + q);
                u32 v = *(const u32*)(X + (size_t)row * F + fbase);
                float x0 = bflo(v), x1 = bfhi(v);
                if constexpr (MODE == 1) {
                    x0 = fmaxf(fmaf(x0, sc0, sh0), 0.f);
                    x1 = fmaxf(fmaf(x1, sc1, sh1), 0.f);
                }
                a0 = fmaf(x0, w, a0);
                a1 = fmaf(x1, w, a1);
            }
        }

        // reduce the 4 edge slots (xor bits 4,5 of lane; fp preserved)
        a0 += __shfl_xor(a0, 16); a0 += __shfl_xor(a0, 32);
        a1 += __shfl_xor(a1, 16); a1 += __shfl_xor(a1, 32);

        if (q == 0) {
            if constexpr (MODE == 2) {
                float2 xr = *(const float2*)(xres + (size_t)i * 256 + fbase);
                float2 o;
                o.x = a0 * di + bb0 + xr.x;
                o.y = a1 * di + bb1 + xr.y;
                *(float2*)(Yf + (size_t)i * 256 + fbase) = o;
            } else {
                u32 o = (u32)f2bf(a0 * di) | ((u32)f2bf(a1 * di) << 16);
                *(u32*)(Y + (size_t)i * F + fbase) = o;
            }
        }
    }
}

// ---------------- bf16 MFMA GEMM: C[M][F] = A[M][K] @ Wt[F][K]^T (+bias f32, +col stats) ----
// 128x128 tile, BK=32, 4 waves each 64x64 (4x4 of 16x16x32 MFMA). C bf16 out.

template <bool STATS, bool BIAS>
__global__ __launch_bounds__(256) void gemm_k(const u16* __restrict__ A, const u16* __restrict__ Wt,
                                              const float* __restrict__ bias, u16* __restrict__ C,
                                              float* __restrict__ colsum, float* __restrict__ colsq,
                                              int M, int K, int F) {
    __shared__ u16 As[128 * 40];
    __shared__ u16 Bs[128 * 40];
    const int m0 = blockIdx.x * 128, f0 = blockIdx.y * 128;
    const int tid = threadIdx.x;
    const int lane = tid & 63, wave = tid >> 6;
    const int waveM = (wave >> 1) * 64, waveN = (wave & 1) * 64;
    const int lrow = tid >> 2, lch = tid & 3;

    f32x4 acc[4][4];
    const f32x4 fz = {0.f, 0.f, 0.f, 0.f};
    #pragma unroll
    for (int i = 0; i < 4; i++)
        #pragma unroll
        for (int j = 0; j < 4; j++) acc[i][j] = fz;

    const int rA0 = m0 + lrow, rA1 = m0 + 64 + lrow;
    const u16* pA0 = A + (size_t)rA0 * K + lch * 8;
    const u16* pA1 = A + (size_t)rA1 * K + lch * 8;
    const u16* pB0 = Wt + (size_t)(f0 + lrow) * K + lch * 8;
    const u16* pB1 = Wt + (size_t)(f0 + 64 + lrow) * K + lch * 8;
    u16* qA0 = &As[lrow * 40 + lch * 8];
    u16* qA1 = &As[(64 + lrow) * 40 + lch * 8];
    u16* qB0 = &Bs[lrow * 40 + lch * 8];
    u16* qB1 = &Bs[(64 + lrow) * 40 + lch * 8];
    const uint4 z4 = {0u, 0u, 0u, 0u};

    const int fm = lane & 15, fq = lane >> 4;

    for (int k0 = 0; k0 < K; k0 += 32) {
        uint4 a0 = (rA0 < M) ? *(const uint4*)(pA0 + k0) : z4;
        uint4 a1 = (rA1 < M) ? *(const uint4*)(pA1 + k0) : z4;
        uint4 b0 = *(const uint4*)(pB0 + k0);
        uint4 b1 = *(const uint4*)(pB1 + k0);
        __syncthreads();
        *(uint4*)qA0 = a0;
        *(uint4*)qA1 = a1;
        *(uint4*)qB0 = b0;
        *(uint4*)qB1 = b1;
        __syncthreads();
        bf16x8 af[4], bfr[4];
        #pragma unroll
        for (int i = 0; i < 4; i++)
            af[i] = *(const bf16x8*)&As[(waveM + i * 16 + fm) * 40 + fq * 8];
        #pragma unroll
        for (int j = 0; j < 4; j++)
            bfr[j] = *(const bf16x8*)&Bs[(waveN + j * 16 + fm) * 40 + fq * 8];
        #pragma unroll
        for (int i = 0; i < 4; i++)
            #pragma unroll
            for (int j = 0; j < 4; j++)
                acc[i][j] = __builtin_amdgcn_mfma_f32_16x16x32_bf16(af[i], bfr[j], acc[i][j], 0, 0, 0);
    }

    // C/D layout: col=lane&15, row=(lane>>4)*4+reg  [learn_hip m89/m91]
    #pragma unroll
    for (int j = 0; j < 4; j++) {
        const int col = f0 + waveN + j * 16 + fm;
        const float bcol = BIAS ? bias[col] : 0.f;
        float s = 0.f, s2 = 0.f;
        #pragma unroll
        for (int i = 0; i < 4; i++) {
            const int rb = m0 + waveM + i * 16 + fq * 4;
            #pragma unroll
            for (int r = 0; r < 4; r++) {
                const int row = rb + r;
                if (row < M) {
                    float v = acc[i][j][r] + bcol;
                    C[(size_t)row * F + col] = f2bf(v);
                    if (STATS) { s += v; s2 += v * v; }
                }
            }
        }
        if (STATS) {
            s += __shfl_xor(s, 16);
            s += __shfl_xor(s, 32);
            s2 += __shfl_xor(s2, 16);
            s2 += __shfl_xor(s2, 32);
            if (fq == 0) {
                atomicAdd(&colsum[col], s);
                atomicAdd(&colsq[col], s2);
            }
        }
    }
}

// ---------------- BN finalize + (standalone) apply ----------------

__global__ __launch_bounds__(256) void bnfin_k(const float* __restrict__ sum, const float* __restrict__ sq,
                                               const float* __restrict__ g, const float* __restrict__ be,
                                               float* __restrict__ scale, float* __restrict__ shift,
                                               int F, float invN) {
    int f = blockIdx.x * 256 + threadIdx.x;
    if (f < F) {
        float m = sum[f] * invN;
        float v = sq[f] * invN - m * m;
        float s = rsqrtf(v + 1e-5f) * g[f];
        scale[f] = s;
        shift[f] = be[f] - m * s;
    }
}

__global__ __launch_bounds__(256) void bnrelu_k(u16* __restrict__ H, const float* __restrict__ scale,
                                                const float* __restrict__ shift, int total, int F) {
    int idx = blockIdx.x * 256 + threadIdx.x;
    int base = idx * 8;
    if (base >= total) return;
    uint4 p = *(const uint4*)(H + base);
    int col = base & (F - 1);
    u32 w[4] = {p.x, p.y, p.z, p.w};
    u32 o[4];
    #pragma unroll
    for (int q = 0; q < 4; q++) {
        float x0 = fmaxf(bflo(w[q]) * scale[col + 2 * q] + shift[col + 2 * q], 0.f);
        float x1 = fmaxf(bfhi(w[q]) * scale[col + 2 * q + 1] + shift[col + 2 * q + 1], 0.f);
        o[q] = ((u32)f2bf(x1) << 16) | (u32)f2bf(x0);
    }
    uint4 po = {o[0], o[1], o[2], o[3]};
    *(uint4*)(H + base) = po;
}

// ---------------- launch ----------------

extern "C" void kernel_launch(void* const* d_in, const int* in_sizes, int n_in,
                              void* d_out, int out_size, void* d_ws, size_t ws_size,
                              hipStream_t stream) {
    const float* x   = (const float*)d_in[0];
    const int*   ei  = (const int*)d_in[1];
    const float* W1  = (const float*)d_in[2];
    const float* b1  = (const float*)d_in[3];
    const float* pg1 = (const float*)d_in[4];
    const float* pbe1= (const float*)d_in[5];
    const float* W2  = (const float*)d_in[6];
    const float* b2  = (const float*)d_in[7];
    const float* pg2 = (const float*)d_in[8];
    const float* pbe2= (const float*)d_in[9];
    const float* W3  = (const float*)d_in[10];
    const float* b3  = (const float*)d_in[11];
    float* out = (float*)d_out;

    char* ws = (char*)d_ws;
    size_t off = 0;
    auto alloc = [&](size_t bytes) -> char* {
        char* p = ws + off;
        off += (bytes + 255) & ~(size_t)255;
        return p;
    };
    float* dinv  = (float*)alloc(NN * 4);
    int*   deg   = (int*)alloc(NN * 4);
    int*   rs    = (int*)alloc(NN * 4);
    int*   cur   = (int*)alloc(NN * 4);
    int*   bsum  = (int*)alloc(256 * 4);
    int*   csr   = (int*)alloc(NE * 4);
    float* stats = (float*)alloc(4 * 512 * 4);
    float* cs1 = stats, *cq1 = stats + 512, *cs2 = stats + 1024, *cq2 = stats + 1536;
    float* scale1 = (float*)alloc(512 * 4);
    float* shift1 = (float*)alloc(512 * 4);
    float* scale2 = (float*)alloc(512 * 4);
    float* shift2 = (float*)alloc(512 * 4);
    u16*   W1t   = (u16*)alloc((size_t)512 * 256 * 2);
    u16*   W2t   = (u16*)alloc((size_t)512 * 512 * 2);
    u16*   W3t   = (u16*)alloc((size_t)256 * 512 * 2);
    u16*   HB    = (u16*)alloc((size_t)NN * 512 * 2);   // 51.2 MB
    u16*   G3    = (u16*)alloc((size_t)NN * 256 * 2);   // 25.6 MB; doubles as XB (x cast to bf16)

    u16* XB = G3;            // bf16 x — lifetime ends before gemm3 writes G3
    u16* A1 = (u16*)d_out;   // bf16 scratch [N,256] in d_out
    u16* A2 = (u16*)d_out;   // bf16 scratch [N,512] in d_out

    const int* srcp = ei;
    const int* dstp = ei + NE;

    hipMemsetAsync(deg, 0, NN * 4, stream);
    hipMemsetAsync(stats, 0, 4 * 512 * 4, stream);

    const int nbN = (NN + 255) / 256;
    count_k<<<(NE + 255) / 256, 256, 0, stream>>>(dstp, deg, NE);
    dinv_k<<<nbN, 256, 0, stream>>>(deg, dinv, NN);
    scan1_k<<<nbN, 256, 0, stream>>>(deg, bsum, NN);
    scan2_k<<<1, 256, 0, stream>>>(bsum, nbN);
    scan3_k<<<nbN, 256, 0, stream>>>(deg, bsum, rs, cur, NN);
    fill_k<<<(NE + 255) / 256, 256, 0, stream>>>(srcp, dstp, cur, csr, NE);

    transpose_k<<<dim3(256 / 32, 512 / 32), 256, 0, stream>>>(W1, W1t, 256, 512);
    transpose_k<<<dim3(512 / 32, 512 / 32), 256, 0, stream>>>(W2, W2t, 512, 512);
    transpose_k<<<dim3(512 / 32, 256 / 32), 256, 0, stream>>>(W3, W3t, 512, 256);

    cast_k<<<NN * 256 / 8 / 256, 256, 0, stream>>>(x, XB, NN * 256);

    const int MT = (NN + 127) / 128;              // 391
    const int AGC = ((NN + 31) / 32) * 8;         // chunked agg: 1563 node-blocks x 8 chunks

    // Layer 1: A1 = Agg(XB) [bf16, d_out]; H1 = A1@W1 + b1 -> HB [bf16] + stats
    aggc_k<256, 0><<<AGC, 256, 0, stream>>>(XB, A1, nullptr, dinv, rs, deg, csr,
                                            nullptr, nullptr, nullptr, nullptr, 0);
    gemm_k<true, true><<<dim3(MT, 4), 256, 0, stream>>>(A1, W1t, b1, HB, cs1, cq1, NN, 256, 512);
    bnfin_k<<<2, 256, 0, stream>>>(cs1, cq1, pg1, pbe1, scale1, shift1, 512, 1.f / NN);

    // Layer 2: A2 = Agg(relu(bn(H1))) fused [bf16, d_out], two 8-chunk passes (feats
    // 0-255 then 256-511) so each XCD slice stays L2-resident; H2 = A2@W2 + b2 -> HB + stats
    aggc_k<512, 1><<<AGC, 256, 0, stream>>>(HB, A2, nullptr, dinv, rs, deg, csr,
                                            scale1, shift1, nullptr, nullptr, 0);
    aggc_k<512, 1><<<AGC, 256, 0, stream>>>(HB, A2, nullptr, dinv, rs, deg, csr,
                                            scale1, shift1, nullptr, nullptr, 8);
    gemm_k<true, true><<<dim3(MT, 4), 256, 0, stream>>>(A2, W2t, b2, HB, cs2, cq2, NN, 512, 512);
    bnfin_k<<<2, 256, 0, stream>>>(cs2, cq2, pg2, pbe2, scale2, shift2, 512, 1.f / NN);
    bnrelu_k<<<NN * 512 / 8 / 256, 256, 0, stream>>>(HB, scale2, shift2, NN * 512, 512);

    // Layer 3: G3 = H2@W3 [bf16, ws, overwrites XB]; out = Agg(G3) + b3 + x [f32, d_out]
    gemm_k<false, false><<<dim3(MT, 2), 256, 0, stream>>>(HB, W3t, nullptr, G3, nullptr, nullptr, NN, 512, 256);
    aggc_k<256, 2><<<AGC, 256, 0, stream>>>(G3, nullptr, out, dinv, rs, deg, csr,
                                            nullptr, nullptr, b3, x, 0);
}

// Round 5
// 693.505 us; speedup vs baseline: 1.5738x; 1.5738x over previous
//
#include <hip/hip_runtime.h>
#include <hip/hip_bf16.h>

#define NN 50000
#define NE 800000

typedef unsigned short u16;
typedef unsigned int   u32;

typedef __attribute__((ext_vector_type(8))) __bf16 bf16x8;
typedef __attribute__((ext_vector_type(4))) float  f32x4;

__device__ __forceinline__ float bf2f(u16 x) {
    u32 u = ((u32)x) << 16;
    return __builtin_bit_cast(float, u);
}
__device__ __forceinline__ u16 f2bf(float f) {
    u32 u = __builtin_bit_cast(u32, f);
    u32 r = (u + 0x7FFFu + ((u >> 16) & 1u)) >> 16;
    return (u16)r;
}
__device__ __forceinline__ float bflo(u32 w) { return __builtin_bit_cast(float, w << 16); }
__device__ __forceinline__ float bfhi(u32 w) { return __builtin_bit_cast(float, w & 0xffff0000u); }

// ---------------- graph preprocessing ----------------

__global__ __launch_bounds__(256) void count_k(const int* __restrict__ dst, int* __restrict__ deg, int E) {
    int e = blockIdx.x * 256 + threadIdx.x;
    if (e < E) atomicAdd(&deg[dst[e]], 1);
}

__global__ __launch_bounds__(256) void dinv_k(const int* __restrict__ deg, float* __restrict__ dinv, int n) {
    int i = blockIdx.x * 256 + threadIdx.x;
    if (i < n) dinv[i] = rsqrtf((float)deg[i] + 1.0f);
}

__global__ __launch_bounds__(256) void scan1_k(const int* __restrict__ deg, int* __restrict__ bsum, int n) {
    __shared__ int sd[256];
    int i = blockIdx.x * 256 + threadIdx.x;
    sd[threadIdx.x] = (i < n) ? deg[i] : 0;
    __syncthreads();
    for (int s = 128; s > 0; s >>= 1) {
        if (threadIdx.x < s) sd[threadIdx.x] += sd[threadIdx.x + s];
        __syncthreads();
    }
    if (threadIdx.x == 0) bsum[blockIdx.x] = sd[0];
}

__global__ __launch_bounds__(256) void scan2_k(int* __restrict__ bsum, int nb) {
    __shared__ int sd[256];
    int t = threadIdx.x;
    int v = (t < nb) ? bsum[t] : 0;
    sd[t] = v;
    __syncthreads();
    for (int off = 1; off < 256; off <<= 1) {
        int tv = (t >= off) ? sd[t - off] : 0;
        __syncthreads();
        sd[t] += tv;
        __syncthreads();
    }
    if (t < nb) bsum[t] = sd[t] - v;  // exclusive
}

__global__ __launch_bounds__(256) void scan3_k(const int* __restrict__ deg, const int* __restrict__ bofs,
                                               int* __restrict__ rs, int* __restrict__ cur, int n) {
    __shared__ int sd[256];
    int t = threadIdx.x;
    int i = blockIdx.x * 256 + t;
    int v = (i < n) ? deg[i] : 0;
    sd[t] = v;
    __syncthreads();
    for (int off = 1; off < 256; off <<= 1) {
        int tv = (t >= off) ? sd[t - off] : 0;
        __syncthreads();
        sd[t] += tv;
        __syncthreads();
    }
    int excl = sd[t] - v + bofs[blockIdx.x];
    if (i < n) { rs[i] = excl; cur[i] = excl; }
}

__global__ __launch_bounds__(256) void fill_k(const int* __restrict__ src, const int* __restrict__ dst,
                                              int* __restrict__ cur, int* __restrict__ csr, int E) {
    int e = blockIdx.x * 256 + threadIdx.x;
    if (e < E) {
        int d = dst[e];
        int pos = atomicAdd(&cur[d], 1);
        csr[pos] = src[e];
    }
}

// ---------------- x f32 -> bf16 cast ----------------

__global__ __launch_bounds__(256) void cast_k(const float* __restrict__ X, u16* __restrict__ Y, int total) {
    int idx = (blockIdx.x * 256 + threadIdx.x) * 8;
    if (idx >= total) return;
    float4 a = *(const float4*)(X + idx);
    float4 b = *(const float4*)(X + idx + 4);
    uint4 o;
    o.x = (u32)f2bf(a.x) | ((u32)f2bf(a.y) << 16);
    o.y = (u32)f2bf(a.z) | ((u32)f2bf(a.w) << 16);
    o.z = (u32)f2bf(b.x) | ((u32)f2bf(b.y) << 16);
    o.w = (u32)f2bf(b.z) | ((u32)f2bf(b.w) << 16);
    *(uint4*)(Y + idx) = o;
}

// ---------------- weight transpose+cast: W f32[K][F] -> Wt bf16[F][K] ----------------

__global__ __launch_bounds__(256) void transpose_k(const float* __restrict__ W, u16* __restrict__ Wt, int K, int F) {
    __shared__ float t[32][33];
    int k0 = blockIdx.x * 32, f0 = blockIdx.y * 32;
    int tx = threadIdx.x & 31, ty = threadIdx.x >> 5;
    for (int r = ty; r < 32; r += 8) t[r][tx] = W[(size_t)(k0 + r) * F + f0 + tx];
    __syncthreads();
    for (int r = ty; r < 32; r += 8) Wt[(size_t)(f0 + r) * K + k0 + tx] = f2bf(t[tx][r]);
}

// ---------------- GCN aggregation, F=512 (round-1 proven wave-per-node) ----------------
// MODE 1 only in practice: BN+ReLU applied to each gathered value, bf16 out. (agg2)

template <int F, int MODE>
__global__ __launch_bounds__(256) void aggu_k(const u16* __restrict__ X, u16* __restrict__ Y,
                                              float* __restrict__ Yf,
                                              const float* __restrict__ dinv, const int* __restrict__ rs,
                                              const int* __restrict__ dg, const int* __restrict__ csr,
                                              const float* __restrict__ scale, const float* __restrict__ shift,
                                              const float* __restrict__ b3, const float* __restrict__ xres) {
    constexpr int FB = F / 64;  // feats per lane (8 at F=512)
    const int tid = threadIdx.x;
    const int lane = tid & 63;
    const int i = blockIdx.x * 4 + (tid >> 6);  // one wave per node
    if (i >= NN) return;
    const int start = rs[i], cnt = dg[i];
    const float di = dinv[i];

    float sc[FB], sh[FB];
    if constexpr (MODE == 1) {
        #pragma unroll
        for (int k = 0; k < FB; k++) {
            sc[k] = scale[lane * FB + k];
            sh[k] = shift[lane * FB + k];
        }
    }

    float acc[FB];
    #pragma unroll
    for (int k = 0; k < FB; k++) acc[k] = 0.f;

    auto gadd = [&](int row, float wgt) {
        float v[FB];
        if constexpr (FB == 4) {
            uint2 p = *(const uint2*)(X + (size_t)row * F + lane * 4);
            v[0] = bflo(p.x); v[1] = bfhi(p.x);
            v[2] = bflo(p.y); v[3] = bfhi(p.y);
        } else {
            uint4 p = *(const uint4*)(X + (size_t)row * F + lane * 8);
            v[0] = bflo(p.x); v[1] = bfhi(p.x);
            v[2] = bflo(p.y); v[3] = bfhi(p.y);
            v[4] = bflo(p.z); v[5] = bfhi(p.z);
            v[6] = bflo(p.w); v[7] = bfhi(p.w);
        }
        #pragma unroll
        for (int k = 0; k < FB; k++) {
            if constexpr (MODE == 1) v[k] = fmaxf(fmaf(v[k], sc[k], sh[k]), 0.f);
            acc[k] = fmaf(v[k], wgt, acc[k]);
        }
    };

    gadd(i, di);  // self-loop term

    for (int base = 0; base < cnt; base += 64) {
        const int m = min(64, cnt - base);
        int   sidx = 0;
        float sw   = 0.f;
        if (lane < m) {
            sidx = csr[start + base + lane];
            sw   = dinv[sidx];
        }
        int j = 0;
        for (; j + 4 <= m; j += 4) {
            int   r0 = __shfl(sidx, j + 0), r1 = __shfl(sidx, j + 1);
            int   r2 = __shfl(sidx, j + 2), r3 = __shfl(sidx, j + 3);
            float w0 = __shfl(sw, j + 0), w1 = __shfl(sw, j + 1);
            float w2 = __shfl(sw, j + 2), w3 = __shfl(sw, j + 3);
            gadd(r0, w0);
            gadd(r1, w1);
            gadd(r2, w2);
            gadd(r3, w3);
        }
        for (; j < m; j++) gadd(__shfl(sidx, j), __shfl(sw, j));
    }

    if constexpr (MODE == 2) {
        float4 xr = *(const float4*)(xres + (size_t)i * 256 + lane * 4);
        float4 bb = *(const float4*)(b3 + lane * 4);
        float4 o;
        o.x = acc[0] * di + bb.x + xr.x;
        o.y = acc[1] * di + bb.y + xr.y;
        o.z = acc[2] * di + bb.z + xr.z;
        o.w = acc[3] * di + bb.w + xr.w;
        *(float4*)(Yf + (size_t)i * 256 + lane * 4) = o;
    } else if constexpr (FB == 4) {
        uint2 o;
        o.x = (u32)f2bf(acc[0] * di) | ((u32)f2bf(acc[1] * di) << 16);
        o.y = (u32)f2bf(acc[2] * di) | ((u32)f2bf(acc[3] * di) << 16);
        *(uint2*)(Y + (size_t)i * F + lane * 4) = o;
    } else {
        uint4 o;
        o.x = (u32)f2bf(acc[0] * di) | ((u32)f2bf(acc[1] * di) << 16);
        o.y = (u32)f2bf(acc[2] * di) | ((u32)f2bf(acc[3] * di) << 16);
        o.z = (u32)f2bf(acc[4] * di) | ((u32)f2bf(acc[5] * di) << 16);
        o.w = (u32)f2bf(acc[6] * di) | ((u32)f2bf(acc[7] * di) << 16);
        *(uint4*)(Y + (size_t)i * F + lane * 8) = o;
    }
}

// ---------------- GCN aggregation, F=256, EDGE-PAIRED ----------------
// Theory (r4): random-row gathers are wave-instruction-rate capped (~equal time for
// 512B and 1KB accesses; 256B was slower). So pack TWO edges per gather instruction:
// lanes 0-31 take edge j (hf=0), lanes 32-63 take edge j+1 (hf=1); each lane loads
// 16B = 8 feats of its half's row -> 1KB per instruction, half the instructions of
// the round-1 uint2 version. Halves merged once at the end via shfl_xor(32).
// MODE 0: plain gather, bf16 out.            (agg1: XB -> A1)
// MODE 2: plain gather + b3 + xres, f32 out. (agg3, final layer)

template <int MODE>
__global__ __launch_bounds__(256) void aggp_k(const u16* __restrict__ X, u16* __restrict__ Y,
                                              float* __restrict__ Yf,
                                              const float* __restrict__ dinv, const int* __restrict__ rs,
                                              const int* __restrict__ dg, const int* __restrict__ csr,
                                              const float* __restrict__ b3, const float* __restrict__ xres) {
    const int tid  = threadIdx.x;
    const int lane = tid & 63;
    const int hf   = lane >> 5;   // edge-pair half 0/1
    const int fl   = lane & 31;   // feat block: covers feats fl*8 .. fl*8+7
    const int i = blockIdx.x * 4 + (tid >> 6);  // one wave per node
    if (i >= NN) return;
    const int start = rs[i], cnt = dg[i];
    const float di = dinv[i];

    float acc[8];
    #pragma unroll
    for (int k = 0; k < 8; k++) acc[k] = 0.f;

    auto gadd = [&](int row, float wgt) {
        uint4 q = *(const uint4*)(X + (size_t)row * 256 + fl * 8);
        float v[8];
        v[0] = bflo(q.x); v[1] = bfhi(q.x);
        v[2] = bflo(q.y); v[3] = bfhi(q.y);
        v[4] = bflo(q.z); v[5] = bfhi(q.z);
        v[6] = bflo(q.w); v[7] = bfhi(q.w);
        #pragma unroll
        for (int k = 0; k < 8; k++) acc[k] = fmaf(v[k], wgt, acc[k]);
    };

    // self-loop: lower half contributes di, upper half 0 (counted once after merge)
    gadd(i, hf ? 0.f : di);

    for (int base = 0; base < cnt; base += 64) {
        const int m = min(64, cnt - base);
        int   sidx = 0;
        float sw   = 0.f;   // lanes >= m keep (row 0, weight 0): zero contribution
        if (lane < m) {
            sidx = csr[start + base + lane];
            sw   = dinv[sidx];
        }
        int j = 0;
        for (; j + 8 <= m; j += 8) {
            int   r0 = __shfl(sidx, j + 0 + hf), r1 = __shfl(sidx, j + 2 + hf);
            int   r2 = __shfl(sidx, j + 4 + hf), r3 = __shfl(sidx, j + 6 + hf);
            float w0 = __shfl(sw, j + 0 + hf), w1 = __shfl(sw, j + 2 + hf);
            float w2 = __shfl(sw, j + 4 + hf), w3 = __shfl(sw, j + 6 + hf);
            gadd(r0, w0);
            gadd(r1, w1);
            gadd(r2, w2);
            gadd(r3, w3);
        }
        for (; j < m; j += 2) {
            // j+hf may equal m when m is odd: lanes >= m hold weight 0 -> safe
            gadd(__shfl(sidx, j + hf), __shfl(sw, j + hf));
        }
    }

    // merge the two edge halves (fl preserved)
    #pragma unroll
    for (int k = 0; k < 8; k++) acc[k] += __shfl_xor(acc[k], 32);

    if (hf == 0) {
        if constexpr (MODE == 2) {
            const float* xr = xres + (size_t)i * 256 + fl * 8;
            float4 x0 = *(const float4*)xr;
            float4 x1 = *(const float4*)(xr + 4);
            float4 b0 = *(const float4*)(b3 + fl * 8);
            float4 b1 = *(const float4*)(b3 + fl * 8 + 4);
            float4 o0, o1;
            o0.x = acc[0] * di + b0.x + x0.x; o0.y = acc[1] * di + b0.y + x0.y;
            o0.z = acc[2] * di + b0.z + x0.z; o0.w = acc[3] * di + b0.w + x0.w;
            o1.x = acc[4] * di + b1.x + x1.x; o1.y = acc[5] * di + b1.y + x1.y;
            o1.z = acc[6] * di + b1.z + x1.z; o1.w = acc[7] * di + b1.w + x1.w;
            float* yp = Yf + (size_t)i * 256 + fl * 8;
            *(float4*)yp = o0;
            *(float4*)(yp + 4) = o1;
        } else {
            uint4 o;
            o.x = (u32)f2bf(acc[0] * di) | ((u32)f2bf(acc[1] * di) << 16);
            o.y = (u32)f2bf(acc[2] * di) | ((u32)f2bf(acc[3] * di) << 16);
            o.z = (u32)f2bf(acc[4] * di) | ((u32)f2bf(acc[5] * di) << 16);
            o.w = (u32)f2bf(acc[6] * di) | ((u32)f2bf(acc[7] * di) << 16);
            *(uint4*)(Y + (size_t)i * 256 + fl * 8) = o;
        }
    }
}

// ---------------- bf16 MFMA GEMM: C[M][F] = A[M][K] @ Wt[F][K]^T (+bias f32, +col stats) ----
// 128x128 tile, BK=32, 4 waves each 64x64 (4x4 of 16x16x32 MFMA). C bf16 out.

template <bool STATS, bool BIAS>
__global__ __launch_bounds__(256) void gemm_k(const u16* __restrict__ A, const u16* __restrict__ Wt,
                                              const float* __restrict__ bias, u16* __restrict__ C,
                                              float* __restrict__ colsum, float* __restrict__ colsq,
                                              int M, int K, int F) {
    __shared__ u16 As[128 * 40];
    __shared__ u16 Bs[128 * 40];
    const int m0 = blockIdx.x * 128, f0 = blockIdx.y * 128;
    const int tid = threadIdx.x;
    const int lane = tid & 63, wave = tid >> 6;
    const int waveM = (wave >> 1) * 64, waveN = (wave & 1) * 64;
    const int lrow = tid >> 2, lch = tid & 3;

    f32x4 acc[4][4];
    const f32x4 fz = {0.f, 0.f, 0.f, 0.f};
    #pragma unroll
    for (int i = 0; i < 4; i++)
        #pragma unroll
        for (int j = 0; j < 4; j++) acc[i][j] = fz;

    const int rA0 = m0 + lrow, rA1 = m0 + 64 + lrow;
    const u16* pA0 = A + (size_t)rA0 * K + lch * 8;
    const u16* pA1 = A + (size_t)rA1 * K + lch * 8;
    const u16* pB0 = Wt + (size_t)(f0 + lrow) * K + lch * 8;
    const u16* pB1 = Wt + (size_t)(f0 + 64 + lrow) * K + lch * 8;
    u16* qA0 = &As[lrow * 40 + lch * 8];
    u16* qA1 = &As[(64 + lrow) * 40 + lch * 8];
    u16* qB0 = &Bs[lrow * 40 + lch * 8];
    u16* qB1 = &Bs[(64 + lrow) * 40 + lch * 8];
    const uint4 z4 = {0u, 0u, 0u, 0u};

    const int fm = lane & 15, fq = lane >> 4;

    for (int k0 = 0; k0 < K; k0 += 32) {
        uint4 a0 = (rA0 < M) ? *(const uint4*)(pA0 + k0) : z4;
        uint4 a1 = (rA1 < M) ? *(const uint4*)(pA1 + k0) : z4;
        uint4 b0 = *(const uint4*)(pB0 + k0);
        uint4 b1 = *(const uint4*)(pB1 + k0);
        __syncthreads();
        *(uint4*)qA0 = a0;
        *(uint4*)qA1 = a1;
        *(uint4*)qB0 = b0;
        *(uint4*)qB1 = b1;
        __syncthreads();
        bf16x8 af[4], bfr[4];
        #pragma unroll
        for (int i = 0; i < 4; i++)
            af[i] = *(const bf16x8*)&As[(waveM + i * 16 + fm) * 40 + fq * 8];
        #pragma unroll
        for (int j = 0; j < 4; j++)
            bfr[j] = *(const bf16x8*)&Bs[(waveN + j * 16 + fm) * 40 + fq * 8];
        #pragma unroll
        for (int i = 0; i < 4; i++)
            #pragma unroll
            for (int j = 0; j < 4; j++)
                acc[i][j] = __builtin_amdgcn_mfma_f32_16x16x32_bf16(af[i], bfr[j], acc[i][j], 0, 0, 0);
    }

    // C/D layout: col=lane&15, row=(lane>>4)*4+reg  [learn_hip m89/m91]
    #pragma unroll
    for (int j = 0; j < 4; j++) {
        const int col = f0 + waveN + j * 16 + fm;
        const float bcol = BIAS ? bias[col] : 0.f;
        float s = 0.f, s2 = 0.f;
        #pragma unroll
        for (int i = 0; i < 4; i++) {
            const int rb = m0 + waveM + i * 16 + fq * 4;
            #pragma unroll
            for (int r = 0; r < 4; r++) {
                const int row = rb + r;
                if (row < M) {
                    float v = acc[i][j][r] + bcol;
                    C[(size_t)row * F + col] = f2bf(v);
                    if (STATS) { s += v; s2 += v * v; }
                }
            }
        }
        if (STATS) {
            s += __shfl_xor(s, 16);
            s += __shfl_xor(s, 32);
            s2 += __shfl_xor(s2, 16);
            s2 += __shfl_xor(s2, 32);
            if (fq == 0) {
                atomicAdd(&colsum[col], s);
                atomicAdd(&colsq[col], s2);
            }
        }
    }
}

// ---------------- BN finalize + (standalone) apply ----------------

__global__ __launch_bounds__(256) void bnfin_k(const float* __restrict__ sum, const float* __restrict__ sq,
                                               const float* __restrict__ g, const float* __restrict__ be,
                                               float* __restrict__ scale, float* __restrict__ shift,
                                               int F, float invN) {
    int f = blockIdx.x * 256 + threadIdx.x;
    if (f < F) {
        float m = sum[f] * invN;
        float v = sq[f] * invN - m * m;
        float s = rsqrtf(v + 1e-5f) * g[f];
        scale[f] = s;
        shift[f] = be[f] - m * s;
    }
}

__global__ __launch_bounds__(256) void bnrelu_k(u16* __restrict__ H, const float* __restrict__ scale,
                                                const float* __restrict__ shift, int total, int F) {
    int idx = blockIdx.x * 256 + threadIdx.x;
    int base = idx * 8;
    if (base >= total) return;
    uint4 p = *(const uint4*)(H + base);
    int col = base & (F - 1);
    u32 w[4] = {p.x, p.y, p.z, p.w};
    u32 o[4];
    #pragma unroll
    for (int q = 0; q < 4; q++) {
        float x0 = fmaxf(bflo(w[q]) * scale[col + 2 * q] + shift[col + 2 * q], 0.f);
        float x1 = fmaxf(bfhi(w[q]) * scale[col + 2 * q + 1] + shift[col + 2 * q + 1], 0.f);
        o[q] = ((u32)f2bf(x1) << 16) | (u32)f2bf(x0);
    }
    uint4 po = {o[0], o[1], o[2], o[3]};
    *(uint4*)(H + base) = po;
}

// ---------------- launch ----------------

extern "C" void kernel_launch(void* const* d_in, const int* in_sizes, int n_in,
                              void* d_out, int out_size, void* d_ws, size_t ws_size,
                              hipStream_t stream) {
    const float* x   = (const float*)d_in[0];
    const int*   ei  = (const int*)d_in[1];
    const float* W1  = (const float*)d_in[2];
    const float* b1  = (const float*)d_in[3];
    const float* pg1 = (const float*)d_in[4];
    const float* pbe1= (const float*)d_in[5];
    const float* W2  = (const float*)d_in[6];
    const float* b2  = (const float*)d_in[7];
    const float* pg2 = (const float*)d_in[8];
    const float* pbe2= (const float*)d_in[9];
    const float* W3  = (const float*)d_in[10];
    const float* b3  = (const float*)d_in[11];
    float* out = (float*)d_out;

    char* ws = (char*)d_ws;
    size_t off = 0;
    auto alloc = [&](size_t bytes) -> char* {
        char* p = ws + off;
        off += (bytes + 255) & ~(size_t)255;
        return p;
    };
    float* dinv  = (float*)alloc(NN * 4);
    int*   deg   = (int*)alloc(NN * 4);
    int*   rs    = (int*)alloc(NN * 4);
    int*   cur   = (int*)alloc(NN * 4);
    int*   bsum  = (int*)alloc(256 * 4);
    int*   csr   = (int*)alloc(NE * 4);
    float* stats = (float*)alloc(4 * 512 * 4);
    float* cs1 = stats, *cq1 = stats + 512, *cs2 = stats + 1024, *cq2 = stats + 1536;
    float* scale1 = (float*)alloc(512 * 4);
    float* shift1 = (float*)alloc(512 * 4);
    float* scale2 = (float*)alloc(512 * 4);
    float* shift2 = (float*)alloc(512 * 4);
    u16*   W1t   = (u16*)alloc((size_t)512 * 256 * 2);
    u16*   W2t   = (u16*)alloc((size_t)512 * 512 * 2);
    u16*   W3t   = (u16*)alloc((size_t)256 * 512 * 2);
    u16*   HB    = (u16*)alloc((size_t)NN * 512 * 2);   // 51.2 MB
    u16*   G3    = (u16*)alloc((size_t)NN * 256 * 2);   // 25.6 MB; doubles as XB (x cast to bf16)

    u16* XB = G3;            // bf16 x — lifetime ends before gemm3 writes G3
    u16* A1 = (u16*)d_out;   // bf16 scratch [N,256] in d_out
    u16* A2 = (u16*)d_out;   // bf16 scratch [N,512] in d_out

    const int* srcp = ei;
    const int* dstp = ei + NE;

    hipMemsetAsync(deg, 0, NN * 4, stream);
    hipMemsetAsync(stats, 0, 4 * 512 * 4, stream);

    const int nbN = (NN + 255) / 256;
    count_k<<<(NE + 255) / 256, 256, 0, stream>>>(dstp, deg, NE);
    dinv_k<<<nbN, 256, 0, stream>>>(deg, dinv, NN);
    scan1_k<<<nbN, 256, 0, stream>>>(deg, bsum, NN);
    scan2_k<<<1, 256, 0, stream>>>(bsum, nbN);
    scan3_k<<<nbN, 256, 0, stream>>>(deg, bsum, rs, cur, NN);
    fill_k<<<(NE + 255) / 256, 256, 0, stream>>>(srcp, dstp, cur, csr, NE);

    transpose_k<<<dim3(256 / 32, 512 / 32), 256, 0, stream>>>(W1, W1t, 256, 512);
    transpose_k<<<dim3(512 / 32, 512 / 32), 256, 0, stream>>>(W2, W2t, 512, 512);
    transpose_k<<<dim3(512 / 32, 256 / 32), 256, 0, stream>>>(W3, W3t, 512, 256);

    cast_k<<<NN * 256 / 8 / 256, 256, 0, stream>>>(x, XB, NN * 256);

    const int MT = (NN + 127) / 128;  // 391
    const int AGB = (NN + 3) / 4;     // wave-per-node agg blocks (4 waves/block)

    // Layer 1: A1 = Agg(XB) [bf16, d_out, edge-paired]; H1 = A1@W1 + b1 -> HB + stats
    aggp_k<0><<<AGB, 256, 0, stream>>>(XB, A1, nullptr, dinv, rs, deg, csr,
                                       nullptr, nullptr);
    gemm_k<true, true><<<dim3(MT, 4), 256, 0, stream>>>(A1, W1t, b1, HB, cs1, cq1, NN, 256, 512);
    bnfin_k<<<2, 256, 0, stream>>>(cs1, cq1, pg1, pbe1, scale1, shift1, 512, 1.f / NN);

    // Layer 2: A2 = Agg(relu(bn(H1))) fused [bf16, d_out]; H2 = A2@W2 + b2 -> HB + stats
    aggu_k<512, 1><<<AGB, 256, 0, stream>>>(HB, A2, nullptr, dinv, rs, deg, csr,
                                            scale1, shift1, nullptr, nullptr);
    gemm_k<true, true><<<dim3(MT, 4), 256, 0, stream>>>(A2, W2t, b2, HB, cs2, cq2, NN, 512, 512);
    bnfin_k<<<2, 256, 0, stream>>>(cs2, cq2, pg2, pbe2, scale2, shift2, 512, 1.f / NN);
    bnrelu_k<<<NN * 512 / 8 / 256, 256, 0, stream>>>(HB, scale2, shift2, NN * 512, 512);

    // Layer 3: G3 = H2@W3 [bf16, ws, overwrites XB]; out = Agg(G3) + b3 + x [f32, edge-paired]
    gemm_k<false, false><<<dim3(MT, 2), 256, 0, stream>>>(HB, W3t, nullptr, G3, nullptr, nullptr, NN, 512, 256);
    aggp_k<2><<<AGB, 256, 0, stream>>>(G3, nullptr, out, dinv, rs, deg, csr,
                                       b3, x);
}

// Round 6
// 693.062 us; speedup vs baseline: 1.5748x; 1.0006x over previous
//
#include <hip/hip_runtime.h>
#include <hip/hip_bf16.h>

#define NN 50000
#define NE 800000

typedef unsigned short u16;
typedef unsigned int   u32;

typedef __attribute__((ext_vector_type(8))) __bf16 bf16x8;
typedef __attribute__((ext_vector_type(4))) float  f32x4;

__device__ __forceinline__ float bf2f(u16 x) {
    u32 u = ((u32)x) << 16;
    return __builtin_bit_cast(float, u);
}
__device__ __forceinline__ u16 f2bf(float f) {
    u32 u = __builtin_bit_cast(u32, f);
    u32 r = (u + 0x7FFFu + ((u >> 16) & 1u)) >> 16;
    return (u16)r;
}
__device__ __forceinline__ float bflo(u32 w) { return __builtin_bit_cast(float, w << 16); }
__device__ __forceinline__ float bfhi(u32 w) { return __builtin_bit_cast(float, w & 0xffff0000u); }

__device__ __forceinline__ int rl_i(int v, int j) {
    return __builtin_amdgcn_readlane(v, j);
}
__device__ __forceinline__ float rl_f(float v, int j) {
    return __builtin_bit_cast(float, __builtin_amdgcn_readlane(__builtin_bit_cast(int, v), j));
}

// async global -> LDS, 16B per lane (HW: wave-uniform LDS base + lane*16; global addr per-lane)
__device__ __forceinline__ void glds16(const u16* g, u16* l) {
    __builtin_amdgcn_global_load_lds((const __attribute__((address_space(1))) void*)g,
                                     (__attribute__((address_space(3))) void*)l, 16, 0, 0);
}

// ---------------- graph preprocessing ----------------

__global__ __launch_bounds__(256) void count_k(const int* __restrict__ dst, int* __restrict__ deg, int E) {
    int e = blockIdx.x * 256 + threadIdx.x;
    if (e < E) atomicAdd(&deg[dst[e]], 1);
}

__global__ __launch_bounds__(256) void dinv_k(const int* __restrict__ deg, float* __restrict__ dinv, int n) {
    int i = blockIdx.x * 256 + threadIdx.x;
    if (i < n) dinv[i] = rsqrtf((float)deg[i] + 1.0f);
}

__global__ __launch_bounds__(256) void scan1_k(const int* __restrict__ deg, int* __restrict__ bsum, int n) {
    __shared__ int sd[256];
    int i = blockIdx.x * 256 + threadIdx.x;
    sd[threadIdx.x] = (i < n) ? deg[i] : 0;
    __syncthreads();
    for (int s = 128; s > 0; s >>= 1) {
        if (threadIdx.x < s) sd[threadIdx.x] += sd[threadIdx.x + s];
        __syncthreads();
    }
    if (threadIdx.x == 0) bsum[blockIdx.x] = sd[0];
}

__global__ __launch_bounds__(256) void scan2_k(int* __restrict__ bsum, int nb) {
    __shared__ int sd[256];
    int t = threadIdx.x;
    int v = (t < nb) ? bsum[t] : 0;
    sd[t] = v;
    __syncthreads();
    for (int off = 1; off < 256; off <<= 1) {
        int tv = (t >= off) ? sd[t - off] : 0;
        __syncthreads();
        sd[t] += tv;
        __syncthreads();
    }
    if (t < nb) bsum[t] = sd[t] - v;  // exclusive
}

__global__ __launch_bounds__(256) void scan3_k(const int* __restrict__ deg, const int* __restrict__ bofs,
                                               int* __restrict__ rs, int* __restrict__ cur, int n) {
    __shared__ int sd[256];
    int t = threadIdx.x;
    int i = blockIdx.x * 256 + t;
    int v = (i < n) ? deg[i] : 0;
    sd[t] = v;
    __syncthreads();
    for (int off = 1; off < 256; off <<= 1) {
        int tv = (t >= off) ? sd[t - off] : 0;
        __syncthreads();
        sd[t] += tv;
        __syncthreads();
    }
    int excl = sd[t] - v + bofs[blockIdx.x];
    if (i < n) { rs[i] = excl; cur[i] = excl; }
}

__global__ __launch_bounds__(256) void fill_k(const int* __restrict__ src, const int* __restrict__ dst,
                                              int* __restrict__ cur, int* __restrict__ csr, int E) {
    int e = blockIdx.x * 256 + threadIdx.x;
    if (e < E) {
        int d = dst[e];
        int pos = atomicAdd(&cur[d], 1);
        csr[pos] = src[e];
    }
}

// ---------------- x f32 -> bf16 cast ----------------

__global__ __launch_bounds__(256) void cast_k(const float* __restrict__ X, u16* __restrict__ Y, int total) {
    int idx = (blockIdx.x * 256 + threadIdx.x) * 8;
    if (idx >= total) return;
    float4 a = *(const float4*)(X + idx);
    float4 b = *(const float4*)(X + idx + 4);
    uint4 o;
    o.x = (u32)f2bf(a.x) | ((u32)f2bf(a.y) << 16);
    o.y = (u32)f2bf(a.z) | ((u32)f2bf(a.w) << 16);
    o.z = (u32)f2bf(b.x) | ((u32)f2bf(b.y) << 16);
    o.w = (u32)f2bf(b.z) | ((u32)f2bf(b.w) << 16);
    *(uint4*)(Y + idx) = o;
}

// ---------------- weight transpose+cast: W f32[K][F] -> Wt bf16[F][K] ----------------

__global__ __launch_bounds__(256) void transpose_k(const float* __restrict__ W, u16* __restrict__ Wt, int K, int F) {
    __shared__ float t[32][33];
    int k0 = blockIdx.x * 32, f0 = blockIdx.y * 32;
    int tx = threadIdx.x & 31, ty = threadIdx.x >> 5;
    for (int r = ty; r < 32; r += 8) t[r][tx] = W[(size_t)(k0 + r) * F + f0 + tx];
    __syncthreads();
    for (int r = ty; r < 32; r += 8) Wt[(size_t)(f0 + r) * K + k0 + tx] = f2bf(t[tx][r]);
}

// ---------------- GCN aggregation, F=512, readlane + unroll-8 (round-3 proven) ----------
// MODE 1: BN+ReLU applied to each gathered value, bf16 out. (agg2)

template <int F, int MODE>
__global__ __launch_bounds__(256) void aggu_k(const u16* __restrict__ X, u16* __restrict__ Y,
                                              float* __restrict__ Yf,
                                              const float* __restrict__ dinv, const int* __restrict__ rs,
                                              const int* __restrict__ dg, const int* __restrict__ csr,
                                              const float* __restrict__ scale, const float* __restrict__ shift,
                                              const float* __restrict__ b3, const float* __restrict__ xres) {
    constexpr int FB = F / 64;  // feats per lane (8 at F=512)
    const int tid = threadIdx.x;
    const int lane = tid & 63;
    const int i = __builtin_amdgcn_readfirstlane(blockIdx.x * 4 + (tid >> 6));
    if (i >= NN) return;
    const int start = rs[i], cnt = dg[i];
    const float di = dinv[i];

    float sc[FB], sh[FB];
    if constexpr (MODE == 1) {
        #pragma unroll
        for (int k = 0; k < FB; k++) {
            sc[k] = scale[lane * FB + k];
            sh[k] = shift[lane * FB + k];
        }
    }

    float acc[FB];
    #pragma unroll
    for (int k = 0; k < FB; k++) acc[k] = 0.f;

    auto gadd = [&](int row, float wgt) {
        // row is wave-uniform (from readlane) -> saddr-form load
        const u16* p = X + (size_t)row * F + lane * FB;
        float v[FB];
        if constexpr (FB == 4) {
            uint2 q = *(const uint2*)p;
            v[0] = bflo(q.x); v[1] = bfhi(q.x);
            v[2] = bflo(q.y); v[3] = bfhi(q.y);
        } else {
            uint4 q = *(const uint4*)p;
            v[0] = bflo(q.x); v[1] = bfhi(q.x);
            v[2] = bflo(q.y); v[3] = bfhi(q.y);
            v[4] = bflo(q.z); v[5] = bfhi(q.z);
            v[6] = bflo(q.w); v[7] = bfhi(q.w);
        }
        #pragma unroll
        for (int k = 0; k < FB; k++) {
            if constexpr (MODE == 1) v[k] = fmaxf(fmaf(v[k], sc[k], sh[k]), 0.f);
            acc[k] = fmaf(v[k], wgt, acc[k]);
        }
    };

    gadd(i, di);  // self-loop term

    for (int base = 0; base < cnt; base += 64) {
        const int m = min(64, cnt - base);
        int   sidx = 0;
        float sw   = 0.f;
        if (lane < m) {
            sidx = csr[start + base + lane];
            sw   = dinv[sidx];
        }
        int j = 0;
        for (; j + 8 <= m; j += 8) {
            int   r[8];
            float w[8];
            #pragma unroll
            for (int q = 0; q < 8; q++) {
                r[q] = rl_i(sidx, j + q);
                w[q] = rl_f(sw, j + q);
            }
            #pragma unroll
            for (int q = 0; q < 8; q++) gadd(r[q], w[q]);
        }
        for (; j < m; j++) gadd(rl_i(sidx, j), rl_f(sw, j));
    }

    if constexpr (MODE == 2) {
        float4 xr = *(const float4*)(xres + (size_t)i * 256 + lane * 4);
        float4 bb = *(const float4*)(b3 + lane * 4);
        float4 o;
        o.x = acc[0] * di + bb.x + xr.x;
        o.y = acc[1] * di + bb.y + xr.y;
        o.z = acc[2] * di + bb.z + xr.z;
        o.w = acc[3] * di + bb.w + xr.w;
        *(float4*)(Yf + (size_t)i * 256 + lane * 4) = o;
    } else if constexpr (FB == 4) {
        uint2 o;
        o.x = (u32)f2bf(acc[0] * di) | ((u32)f2bf(acc[1] * di) << 16);
        o.y = (u32)f2bf(acc[2] * di) | ((u32)f2bf(acc[3] * di) << 16);
        *(uint2*)(Y + (size_t)i * F + lane * 4) = o;
    } else {
        uint4 o;
        o.x = (u32)f2bf(acc[0] * di) | ((u32)f2bf(acc[1] * di) << 16);
        o.y = (u32)f2bf(acc[2] * di) | ((u32)f2bf(acc[3] * di) << 16);
        o.z = (u32)f2bf(acc[4] * di) | ((u32)f2bf(acc[5] * di) << 16);
        o.w = (u32)f2bf(acc[6] * di) | ((u32)f2bf(acc[7] * di) << 16);
        *(uint4*)(Y + (size_t)i * F + lane * 8) = o;
    }
}

// ---------------- GCN aggregation, F=256, EDGE-PAIRED (round-5, neutral-proven) -------
// lanes 0-31 take edge j, lanes 32-63 edge j+1; 16B/lane -> 1KB per gather instr.
// MODE 0: plain gather, bf16 out.            (agg1: XB -> A1)
// MODE 2: plain gather + b3 + xres, f32 out. (agg3, final layer)

template <int MODE>
__global__ __launch_bounds__(256) void aggp_k(const u16* __restrict__ X, u16* __restrict__ Y,
                                              float* __restrict__ Yf,
                                              const float* __restrict__ dinv, const int* __restrict__ rs,
                                              const int* __restrict__ dg, const int* __restrict__ csr,
                                              const float* __restrict__ b3, const float* __restrict__ xres) {
    const int tid  = threadIdx.x;
    const int lane = tid & 63;
    const int hf   = lane >> 5;   // edge-pair half 0/1
    const int fl   = lane & 31;   // feat block: covers feats fl*8 .. fl*8+7
    const int i = blockIdx.x * 4 + (tid >> 6);  // one wave per node
    if (i >= NN) return;
    const int start = rs[i], cnt = dg[i];
    const float di = dinv[i];

    float acc[8];
    #pragma unroll
    for (int k = 0; k < 8; k++) acc[k] = 0.f;

    auto gadd = [&](int row, float wgt) {
        uint4 q = *(const uint4*)(X + (size_t)row * 256 + fl * 8);
        float v[8];
        v[0] = bflo(q.x); v[1] = bfhi(q.x);
        v[2] = bflo(q.y); v[3] = bfhi(q.y);
        v[4] = bflo(q.z); v[5] = bfhi(q.z);
        v[6] = bflo(q.w); v[7] = bfhi(q.w);
        #pragma unroll
        for (int k = 0; k < 8; k++) acc[k] = fmaf(v[k], wgt, acc[k]);
    };

    // self-loop: lower half contributes di, upper half 0 (counted once after merge)
    gadd(i, hf ? 0.f : di);

    for (int base = 0; base < cnt; base += 64) {
        const int m = min(64, cnt - base);
        int   sidx = 0;
        float sw   = 0.f;   // lanes >= m keep (row 0, weight 0): zero contribution
        if (lane < m) {
            sidx = csr[start + base + lane];
            sw   = dinv[sidx];
        }
        int j = 0;
        for (; j + 8 <= m; j += 8) {
            int   r0 = __shfl(sidx, j + 0 + hf), r1 = __shfl(sidx, j + 2 + hf);
            int   r2 = __shfl(sidx, j + 4 + hf), r3 = __shfl(sidx, j + 6 + hf);
            float w0 = __shfl(sw, j + 0 + hf), w1 = __shfl(sw, j + 2 + hf);
            float w2 = __shfl(sw, j + 4 + hf), w3 = __shfl(sw, j + 6 + hf);
            gadd(r0, w0);
            gadd(r1, w1);
            gadd(r2, w2);
            gadd(r3, w3);
        }
        for (; j < m; j += 2) {
            // j+hf may equal m when m is odd: lanes >= m hold weight 0 -> safe
            gadd(__shfl(sidx, j + hf), __shfl(sw, j + hf));
        }
    }

    // merge the two edge halves (fl preserved)
    #pragma unroll
    for (int k = 0; k < 8; k++) acc[k] += __shfl_xor(acc[k], 32);

    if (hf == 0) {
        if constexpr (MODE == 2) {
            const float* xr = xres + (size_t)i * 256 + fl * 8;
            float4 x0 = *(const float4*)xr;
            float4 x1 = *(const float4*)(xr + 4);
            float4 b0 = *(const float4*)(b3 + fl * 8);
            float4 b1 = *(const float4*)(b3 + fl * 8 + 4);
            float4 o0, o1;
            o0.x = acc[0] * di + b0.x + x0.x; o0.y = acc[1] * di + b0.y + x0.y;
            o0.z = acc[2] * di + b0.z + x0.z; o0.w = acc[3] * di + b0.w + x0.w;
            o1.x = acc[4] * di + b1.x + x1.x; o1.y = acc[5] * di + b1.y + x1.y;
            o1.z = acc[6] * di + b1.z + x1.z; o1.w = acc[7] * di + b1.w + x1.w;
            float* yp = Yf + (size_t)i * 256 + fl * 8;
            *(float4*)yp = o0;
            *(float4*)(yp + 4) = o1;
        } else {
            uint4 o;
            o.x = (u32)f2bf(acc[0] * di) | ((u32)f2bf(acc[1] * di) << 16);
            o.y = (u32)f2bf(acc[2] * di) | ((u32)f2bf(acc[3] * di) << 16);
            o.z = (u32)f2bf(acc[4] * di) | ((u32)f2bf(acc[5] * di) << 16);
            o.w = (u32)f2bf(acc[6] * di) | ((u32)f2bf(acc[7] * di) << 16);
            *(uint4*)(Y + (size_t)i * 256 + fl * 8) = o;
        }
    }
}

// ---------------- bf16 MFMA GEMM: C[M][F] = A[M][K] @ Wt[F][K]^T (+bias, +col stats) ----
// 128x128 tile, BK=32, 4 waves each 64x64 (4x4 of 16x16x32 MFMA). C bf16 out.
// Staging via global_load_lds width-16 (m97 ladder: reg-stage 646 -> glds 874 TF at 128²).
// LDS layout UNPADDED [128][32]: thread tid's (row=tid>>2, chunk=tid&3) slot = byte
// tid*16 -> exactly the wave-uniform-base + lane*16 pattern glds requires.
// OOB tail rows: clamp the per-lane GLOBAL source address (per-lane src is legal);
// stores stay predicated on row < M.

template <bool STATS, bool BIAS>
__global__ __launch_bounds__(256) void gemm_k(const u16* __restrict__ A, const u16* __restrict__ Wt,
                                              const float* __restrict__ bias, u16* __restrict__ C,
                                              float* __restrict__ colsum, float* __restrict__ colsq,
                                              int M, int K, int F) {
    __shared__ u16 As[128 * 32];
    __shared__ u16 Bs[128 * 32];
    const int m0 = blockIdx.x * 128, f0 = blockIdx.y * 128;
    const int tid = threadIdx.x;
    const int lane = tid & 63, wave = tid >> 6;
    const int waveM = (wave >> 1) * 64, waveN = (wave & 1) * 64;
    const int lrow = tid >> 2, lch = tid & 3;

    f32x4 acc[4][4];
    const f32x4 fz = {0.f, 0.f, 0.f, 0.f};
    #pragma unroll
    for (int i = 0; i < 4; i++)
        #pragma unroll
        for (int j = 0; j < 4; j++) acc[i][j] = fz;

    const int rA0 = m0 + lrow, rA1 = m0 + 64 + lrow;
    const int cA0 = (rA0 < M) ? rA0 : (M - 1);
    const int cA1 = (rA1 < M) ? rA1 : (M - 1);
    const u16* pA0 = A + (size_t)cA0 * K + lch * 8;
    const u16* pA1 = A + (size_t)cA1 * K + lch * 8;
    const u16* pB0 = Wt + (size_t)(f0 + lrow) * K + lch * 8;
    const u16* pB1 = Wt + (size_t)(f0 + 64 + lrow) * K + lch * 8;
    u16* qA0 = &As[tid * 8];
    u16* qA1 = &As[2048 + tid * 8];
    u16* qB0 = &Bs[tid * 8];
    u16* qB1 = &Bs[2048 + tid * 8];

    const int fm = lane & 15, fq = lane >> 4;

    for (int k0 = 0; k0 < K; k0 += 32) {
        __syncthreads();   // previous iteration's LDS reads complete
        glds16(pA0 + k0, qA0);
        glds16(pA1 + k0, qA1);
        glds16(pB0 + k0, qB0);
        glds16(pB1 + k0, qB1);
        __syncthreads();   // vmcnt(0) drain before barrier -> LDS tile ready
        bf16x8 af[4], bfr[4];
        #pragma unroll
        for (int i = 0; i < 4; i++)
            af[i] = *(const bf16x8*)&As[(waveM + i * 16 + fm) * 32 + fq * 8];
        #pragma unroll
        for (int j = 0; j < 4; j++)
            bfr[j] = *(const bf16x8*)&Bs[(waveN + j * 16 + fm) * 32 + fq * 8];
        #pragma unroll
        for (int i = 0; i < 4; i++)
            #pragma unroll
            for (int j = 0; j < 4; j++)
                acc[i][j] = __builtin_amdgcn_mfma_f32_16x16x32_bf16(af[i], bfr[j], acc[i][j], 0, 0, 0);
    }

    // C/D layout: col=lane&15, row=(lane>>4)*4+reg  [learn_hip m89/m91]
    #pragma unroll
    for (int j = 0; j < 4; j++) {
        const int col = f0 + waveN + j * 16 + fm;
        const float bcol = BIAS ? bias[col] : 0.f;
        float s = 0.f, s2 = 0.f;
        #pragma unroll
        for (int i = 0; i < 4; i++) {
            const int rb = m0 + waveM + i * 16 + fq * 4;
            #pragma unroll
            for (int r = 0; r < 4; r++) {
                const int row = rb + r;
                if (row < M) {
                    float v = acc[i][j][r] + bcol;
                    C[(size_t)row * F + col] = f2bf(v);
                    if (STATS) { s += v; s2 += v * v; }
                }
            }
        }
        if (STATS) {
            s += __shfl_xor(s, 16);
            s += __shfl_xor(s, 32);
            s2 += __shfl_xor(s2, 16);
            s2 += __shfl_xor(s2, 32);
            if (fq == 0) {
                atomicAdd(&colsum[col], s);
                atomicAdd(&colsq[col], s2);
            }
        }
    }
}

// ---------------- BN finalize + (standalone) apply ----------------

__global__ __launch_bounds__(256) void bnfin_k(const float* __restrict__ sum, const float* __restrict__ sq,
                                               const float* __restrict__ g, const float* __restrict__ be,
                                               float* __restrict__ scale, float* __restrict__ shift,
                                               int F, float invN) {
    int f = blockIdx.x * 256 + threadIdx.x;
    if (f < F) {
        float m = sum[f] * invN;
        float v = sq[f] * invN - m * m;
        float s = rsqrtf(v + 1e-5f) * g[f];
        scale[f] = s;
        shift[f] = be[f] - m * s;
    }
}

__global__ __launch_bounds__(256) void bnrelu_k(u16* __restrict__ H, const float* __restrict__ scale,
                                                const float* __restrict__ shift, int total, int F) {
    int idx = blockIdx.x * 256 + threadIdx.x;
    int base = idx * 8;
    if (base >= total) return;
    uint4 p = *(const uint4*)(H + base);
    int col = base & (F - 1);
    u32 w[4] = {p.x, p.y, p.z, p.w};
    u32 o[4];
    #pragma unroll
    for (int q = 0; q < 4; q++) {
        float x0 = fmaxf(bflo(w[q]) * scale[col + 2 * q] + shift[col + 2 * q], 0.f);
        float x1 = fmaxf(bfhi(w[q]) * scale[col + 2 * q + 1] + shift[col + 2 * q + 1], 0.f);
        o[q] = ((u32)f2bf(x1) << 16) | (u32)f2bf(x0);
    }
    uint4 po = {o[0], o[1], o[2], o[3]};
    *(uint4*)(H + base) = po;
}

// ---------------- launch ----------------

extern "C" void kernel_launch(void* const* d_in, const int* in_sizes, int n_in,
                              void* d_out, int out_size, void* d_ws, size_t ws_size,
                              hipStream_t stream) {
    const float* x   = (const float*)d_in[0];
    const int*   ei  = (const int*)d_in[1];
    const float* W1  = (const float*)d_in[2];
    const float* b1  = (const float*)d_in[3];
    const float* pg1 = (const float*)d_in[4];
    const float* pbe1= (const float*)d_in[5];
    const float* W2  = (const float*)d_in[6];
    const float* b2  = (const float*)d_in[7];
    const float* pg2 = (const float*)d_in[8];
    const float* pbe2= (const float*)d_in[9];
    const float* W3  = (const float*)d_in[10];
    const float* b3  = (const float*)d_in[11];
    float* out = (float*)d_out;

    char* ws = (char*)d_ws;
    size_t off = 0;
    auto alloc = [&](size_t bytes) -> char* {
        char* p = ws + off;
        off += (bytes + 255) & ~(size_t)255;
        return p;
    };
    float* dinv  = (float*)alloc(NN * 4);
    int*   deg   = (int*)alloc(NN * 4);
    int*   rs    = (int*)alloc(NN * 4);
    int*   cur   = (int*)alloc(NN * 4);
    int*   bsum  = (int*)alloc(256 * 4);
    int*   csr   = (int*)alloc(NE * 4);
    float* stats = (float*)alloc(4 * 512 * 4);
    float* cs1 = stats, *cq1 = stats + 512, *cs2 = stats + 1024, *cq2 = stats + 1536;
    float* scale1 = (float*)alloc(512 * 4);
    float* shift1 = (float*)alloc(512 * 4);
    float* scale2 = (float*)alloc(512 * 4);
    float* shift2 = (float*)alloc(512 * 4);
    u16*   W1t   = (u16*)alloc((size_t)512 * 256 * 2);
    u16*   W2t   = (u16*)alloc((size_t)512 * 512 * 2);
    u16*   W3t   = (u16*)alloc((size_t)256 * 512 * 2);
    u16*   HB    = (u16*)alloc((size_t)NN * 512 * 2);   // 51.2 MB
    u16*   G3    = (u16*)alloc((size_t)NN * 256 * 2);   // 25.6 MB; doubles as XB (x cast to bf16)

    u16* XB = G3;            // bf16 x — lifetime ends before gemm3 writes G3
    u16* A1 = (u16*)d_out;   // bf16 scratch [N,256] in d_out
    u16* A2 = (u16*)d_out;   // bf16 scratch [N,512] in d_out

    const int* srcp = ei;
    const int* dstp = ei + NE;

    hipMemsetAsync(deg, 0, NN * 4, stream);
    hipMemsetAsync(stats, 0, 4 * 512 * 4, stream);

    const int nbN = (NN + 255) / 256;
    count_k<<<(NE + 255) / 256, 256, 0, stream>>>(dstp, deg, NE);
    dinv_k<<<nbN, 256, 0, stream>>>(deg, dinv, NN);
    scan1_k<<<nbN, 256, 0, stream>>>(deg, bsum, NN);
    scan2_k<<<1, 256, 0, stream>>>(bsum, nbN);
    scan3_k<<<nbN, 256, 0, stream>>>(deg, bsum, rs, cur, NN);
    fill_k<<<(NE + 255) / 256, 256, 0, stream>>>(srcp, dstp, cur, csr, NE);

    transpose_k<<<dim3(256 / 32, 512 / 32), 256, 0, stream>>>(W1, W1t, 256, 512);
    transpose_k<<<dim3(512 / 32, 512 / 32), 256, 0, stream>>>(W2, W2t, 512, 512);
    transpose_k<<<dim3(512 / 32, 256 / 32), 256, 0, stream>>>(W3, W3t, 512, 256);

    cast_k<<<NN * 256 / 8 / 256, 256, 0, stream>>>(x, XB, NN * 256);

    const int MT = (NN + 127) / 128;  // 391
    const int AGB = (NN + 3) / 4;     // wave-per-node agg blocks (4 waves/block)

    // Layer 1: A1 = Agg(XB) [bf16, d_out, edge-paired]; H1 = A1@W1 + b1 -> HB + stats
    aggp_k<0><<<AGB, 256, 0, stream>>>(XB, A1, nullptr, dinv, rs, deg, csr,
                                       nullptr, nullptr);
    gemm_k<true, true><<<dim3(MT, 4), 256, 0, stream>>>(A1, W1t, b1, HB, cs1, cq1, NN, 256, 512);
    bnfin_k<<<2, 256, 0, stream>>>(cs1, cq1, pg1, pbe1, scale1, shift1, 512, 1.f / NN);

    // Layer 2: A2 = Agg(relu(bn(H1))) fused [bf16, d_out]; H2 = A2@W2 + b2 -> HB + stats
    aggu_k<512, 1><<<AGB, 256, 0, stream>>>(HB, A2, nullptr, dinv, rs, deg, csr,
                                            scale1, shift1, nullptr, nullptr);
    gemm_k<true, true><<<dim3(MT, 4), 256, 0, stream>>>(A2, W2t, b2, HB, cs2, cq2, NN, 512, 512);
    bnfin_k<<<2, 256, 0, stream>>>(cs2, cq2, pg2, pbe2, scale2, shift2, 512, 1.f / NN);
    bnrelu_k<<<NN * 512 / 8 / 256, 256, 0, stream>>>(HB, scale2, shift2, NN * 512, 512);

    // Layer 3: G3 = H2@W3 [bf16, ws, overwrites XB]; out = Agg(G3) + b3 + x [f32, edge-paired]
    gemm_k<false, false><<<dim3(MT, 2), 256, 0, stream>>>(HB, W3t, nullptr, G3, nullptr, nullptr, NN, 512, 256);
    aggp_k<2><<<AGB, 256, 0, stream>>>(G3, nullptr, out, dinv, rs, deg, csr,
                                       b3, x);
}

// Round 7
// 690.349 us; speedup vs baseline: 1.5810x; 1.0039x over previous
//
#include <hip/hip_runtime.h>
#include <hip/hip_bf16.h>

#define NN 50000
#define NE 800000

typedef unsigned short u16;
typedef unsigned int   u32;

typedef __attribute__((ext_vector_type(8))) __bf16 bf16x8;
typedef __attribute__((ext_vector_type(4))) float  f32x4;

__device__ __forceinline__ float bf2f(u16 x) {
    u32 u = ((u32)x) << 16;
    return __builtin_bit_cast(float, u);
}
__device__ __forceinline__ u16 f2bf(float f) {
    u32 u = __builtin_bit_cast(u32, f);
    u32 r = (u + 0x7FFFu + ((u >> 16) & 1u)) >> 16;
    return (u16)r;
}
__device__ __forceinline__ float bflo(u32 w) { return __builtin_bit_cast(float, w << 16); }
__device__ __forceinline__ float bfhi(u32 w) { return __builtin_bit_cast(float, w & 0xffff0000u); }

__device__ __forceinline__ int rl_i(int v, int j) {
    return __builtin_amdgcn_readlane(v, j);
}
__device__ __forceinline__ float rl_f(float v, int j) {
    return __builtin_bit_cast(float, __builtin_amdgcn_readlane(__builtin_bit_cast(int, v), j));
}

// async global -> LDS, 16B per lane (HW: wave-uniform LDS base + lane*16; global addr per-lane)
__device__ __forceinline__ void glds16(const u16* g, u16* l) {
    __builtin_amdgcn_global_load_lds((const __attribute__((address_space(1))) void*)g,
                                     (__attribute__((address_space(3))) void*)l, 16, 0, 0);
}

// ---------------- graph preprocessing ----------------

__global__ __launch_bounds__(256) void count_k(const int* __restrict__ dst, int* __restrict__ deg, int E) {
    int e = blockIdx.x * 256 + threadIdx.x;
    if (e < E) atomicAdd(&deg[dst[e]], 1);
}

// scan1 + dinv fused (deg is final here; dinv = rsqrt(deg+1))
__global__ __launch_bounds__(256) void scan1_k(const int* __restrict__ deg, float* __restrict__ dinv,
                                               int* __restrict__ bsum, int n) {
    __shared__ int sd[256];
    int i = blockIdx.x * 256 + threadIdx.x;
    int v = (i < n) ? deg[i] : 0;
    if (i < n) dinv[i] = rsqrtf((float)v + 1.0f);
    sd[threadIdx.x] = v;
    __syncthreads();
    for (int s = 128; s > 0; s >>= 1) {
        if (threadIdx.x < s) sd[threadIdx.x] += sd[threadIdx.x + s];
        __syncthreads();
    }
    if (threadIdx.x == 0) bsum[blockIdx.x] = sd[0];
}

__global__ __launch_bounds__(256) void scan2_k(int* __restrict__ bsum, int nb) {
    __shared__ int sd[256];
    int t = threadIdx.x;
    int v = (t < nb) ? bsum[t] : 0;
    sd[t] = v;
    __syncthreads();
    for (int off = 1; off < 256; off <<= 1) {
        int tv = (t >= off) ? sd[t - off] : 0;
        __syncthreads();
        sd[t] += tv;
        __syncthreads();
    }
    if (t < nb) bsum[t] = sd[t] - v;  // exclusive
}

__global__ __launch_bounds__(256) void scan3_k(const int* __restrict__ deg, const int* __restrict__ bofs,
                                               int* __restrict__ rs, int* __restrict__ cur, int n) {
    __shared__ int sd[256];
    int t = threadIdx.x;
    int i = blockIdx.x * 256 + t;
    int v = (i < n) ? deg[i] : 0;
    sd[t] = v;
    __syncthreads();
    for (int off = 1; off < 256; off <<= 1) {
        int tv = (t >= off) ? sd[t - off] : 0;
        __syncthreads();
        sd[t] += tv;
        __syncthreads();
    }
    int excl = sd[t] - v + bofs[blockIdx.x];
    if (i < n) { rs[i] = excl; cur[i] = excl; }
}

__global__ __launch_bounds__(256) void fill_k(const int* __restrict__ src, const int* __restrict__ dst,
                                              int* __restrict__ cur, int* __restrict__ csr, int E) {
    int e = blockIdx.x * 256 + threadIdx.x;
    if (e < E) {
        int d = dst[e];
        int pos = atomicAdd(&cur[d], 1);
        csr[pos] = src[e];
    }
}

// ---------------- x f32 -> bf16 cast ----------------

__global__ __launch_bounds__(256) void cast_k(const float* __restrict__ X, u16* __restrict__ Y, int total) {
    int idx = (blockIdx.x * 256 + threadIdx.x) * 8;
    if (idx >= total) return;
    float4 a = *(const float4*)(X + idx);
    float4 b = *(const float4*)(X + idx + 4);
    uint4 o;
    o.x = (u32)f2bf(a.x) | ((u32)f2bf(a.y) << 16);
    o.y = (u32)f2bf(a.z) | ((u32)f2bf(a.w) << 16);
    o.z = (u32)f2bf(b.x) | ((u32)f2bf(b.y) << 16);
    o.w = (u32)f2bf(b.z) | ((u32)f2bf(b.w) << 16);
    *(uint4*)(Y + idx) = o;
}

// ---------------- all three weight transposes in ONE launch ----------------
// W f32[K][F] -> Wt bf16[F][K]. 512 blocks: 128 (W1 8x16 tiles) + 256 (W2) + 128 (W3).

__global__ __launch_bounds__(256) void transpose_all_k(const float* __restrict__ W1, u16* __restrict__ W1t,
                                                       const float* __restrict__ W2, u16* __restrict__ W2t,
                                                       const float* __restrict__ W3, u16* __restrict__ W3t) {
    int b = blockIdx.x;
    const float* W; u16* Wt; int K, F, t;
    if (b < 128)      { W = W1; Wt = W1t; K = 256; F = 512; t = b; }
    else if (b < 384) { W = W2; Wt = W2t; K = 512; F = 512; t = b - 128; }
    else              { W = W3; Wt = W3t; K = 512; F = 256; t = b - 384; }
    const int kt = K / 32;
    const int k0 = (t % kt) * 32, f0 = (t / kt) * 32;
    __shared__ float tt[32][33];
    int tx = threadIdx.x & 31, ty = threadIdx.x >> 5;
    for (int r = ty; r < 32; r += 8) tt[r][tx] = W[(size_t)(k0 + r) * F + f0 + tx];
    __syncthreads();
    for (int r = ty; r < 32; r += 8) Wt[(size_t)(f0 + r) * K + k0 + tx] = f2bf(tt[tx][r]);
}

// ---------------- agg2: F=512, wave-per-node, BN-finalize FOLDED ----------------
// Each block first computes the 512 scale/shift values from the gemm1 column sums
// (bnfin math inlined -> bnfin1 dispatch removed), then gathers with BN+ReLU applied
// per value. readlane broadcast + unroll-8 (round-3/6 proven). Launched as TWO
// half-node grids (base 0 / 25000) -> vacates the rocprof top-5 for visibility.

__global__ __launch_bounds__(256) void agg2_k(const u16* __restrict__ X, u16* __restrict__ Y,
                                              const float* __restrict__ dinv, const int* __restrict__ rs,
                                              const int* __restrict__ dg, const int* __restrict__ csr,
                                              const float* __restrict__ cs, const float* __restrict__ cq,
                                              const float* __restrict__ g, const float* __restrict__ be,
                                              int base) {
    __shared__ float lsc[512], lsh[512];
    const int tid = threadIdx.x;
    for (int f = tid; f < 512; f += 256) {
        float m = cs[f] * (1.f / NN);
        float v = cq[f] * (1.f / NN) - m * m;
        float s = rsqrtf(v + 1e-5f) * g[f];
        lsc[f] = s;
        lsh[f] = be[f] - m * s;
    }
    __syncthreads();

    const int lane = tid & 63;
    const int i = __builtin_amdgcn_readfirstlane(base + blockIdx.x * 4 + (tid >> 6));
    if (i >= NN) return;
    const int start = rs[i], cnt = dg[i];
    const float di = dinv[i];

    float sc[8], sh[8];
    #pragma unroll
    for (int k = 0; k < 8; k++) {
        sc[k] = lsc[lane * 8 + k];
        sh[k] = lsh[lane * 8 + k];
    }

    float acc[8];
    #pragma unroll
    for (int k = 0; k < 8; k++) acc[k] = 0.f;

    auto gadd = [&](int row, float wgt) {
        const u16* p = X + (size_t)row * 512 + lane * 8;
        uint4 q = *(const uint4*)p;
        float v[8];
        v[0] = bflo(q.x); v[1] = bfhi(q.x);
        v[2] = bflo(q.y); v[3] = bfhi(q.y);
        v[4] = bflo(q.z); v[5] = bfhi(q.z);
        v[6] = bflo(q.w); v[7] = bfhi(q.w);
        #pragma unroll
        for (int k = 0; k < 8; k++) {
            float x = fmaxf(fmaf(v[k], sc[k], sh[k]), 0.f);
            acc[k] = fmaf(x, wgt, acc[k]);
        }
    };

    gadd(i, di);  // self-loop term

    for (int bse = 0; bse < cnt; bse += 64) {
        const int m = min(64, cnt - bse);
        int   sidx = 0;
        float sw   = 0.f;
        if (lane < m) {
            sidx = csr[start + bse + lane];
            sw   = dinv[sidx];
        }
        int j = 0;
        for (; j + 8 <= m; j += 8) {
            int   r[8];
            float w[8];
            #pragma unroll
            for (int q = 0; q < 8; q++) {
                r[q] = rl_i(sidx, j + q);
                w[q] = rl_f(sw, j + q);
            }
            #pragma unroll
            for (int q = 0; q < 8; q++) gadd(r[q], w[q]);
        }
        for (; j < m; j++) gadd(rl_i(sidx, j), rl_f(sw, j));
    }

    uint4 o;
    o.x = (u32)f2bf(acc[0] * di) | ((u32)f2bf(acc[1] * di) << 16);
    o.y = (u32)f2bf(acc[2] * di) | ((u32)f2bf(acc[3] * di) << 16);
    o.z = (u32)f2bf(acc[4] * di) | ((u32)f2bf(acc[5] * di) << 16);
    o.w = (u32)f2bf(acc[6] * di) | ((u32)f2bf(acc[7] * di) << 16);
    *(uint4*)(Y + (size_t)i * 512 + lane * 8) = o;
}

// ---------------- GCN aggregation, F=256, EDGE-PAIRED (round-5/6 proven) -------
// lanes 0-31 take edge j, lanes 32-63 edge j+1; 16B/lane -> 1KB per gather instr.
// MODE 0: plain gather, bf16 out.            (agg1: XB -> A1)
// MODE 2: plain gather + b3 + xres, f32 out. (agg3, final layer)

template <int MODE>
__global__ __launch_bounds__(256) void aggp_k(const u16* __restrict__ X, u16* __restrict__ Y,
                                              float* __restrict__ Yf,
                                              const float* __restrict__ dinv, const int* __restrict__ rs,
                                              const int* __restrict__ dg, const int* __restrict__ csr,
                                              const float* __restrict__ b3, const float* __restrict__ xres) {
    const int tid  = threadIdx.x;
    const int lane = tid & 63;
    const int hf   = lane >> 5;   // edge-pair half 0/1
    const int fl   = lane & 31;   // feat block: covers feats fl*8 .. fl*8+7
    const int i = blockIdx.x * 4 + (tid >> 6);  // one wave per node
    if (i >= NN) return;
    const int start = rs[i], cnt = dg[i];
    const float di = dinv[i];

    float acc[8];
    #pragma unroll
    for (int k = 0; k < 8; k++) acc[k] = 0.f;

    auto gadd = [&](int row, float wgt) {
        uint4 q = *(const uint4*)(X + (size_t)row * 256 + fl * 8);
        float v[8];
        v[0] = bflo(q.x); v[1] = bfhi(q.x);
        v[2] = bflo(q.y); v[3] = bfhi(q.y);
        v[4] = bflo(q.z); v[5] = bfhi(q.z);
        v[6] = bflo(q.w); v[7] = bfhi(q.w);
        #pragma unroll
        for (int k = 0; k < 8; k++) acc[k] = fmaf(v[k], wgt, acc[k]);
    };

    // self-loop: lower half contributes di, upper half 0 (counted once after merge)
    gadd(i, hf ? 0.f : di);

    for (int bse = 0; bse < cnt; bse += 64) {
        const int m = min(64, cnt - bse);
        int   sidx = 0;
        float sw   = 0.f;   // lanes >= m keep (row 0, weight 0): zero contribution
        if (lane < m) {
            sidx = csr[start + bse + lane];
            sw   = dinv[sidx];
        }
        int j = 0;
        for (; j + 8 <= m; j += 8) {
            int   r0 = __shfl(sidx, j + 0 + hf), r1 = __shfl(sidx, j + 2 + hf);
            int   r2 = __shfl(sidx, j + 4 + hf), r3 = __shfl(sidx, j + 6 + hf);
            float w0 = __shfl(sw, j + 0 + hf), w1 = __shfl(sw, j + 2 + hf);
            float w2 = __shfl(sw, j + 4 + hf), w3 = __shfl(sw, j + 6 + hf);
            gadd(r0, w0);
            gadd(r1, w1);
            gadd(r2, w2);
            gadd(r3, w3);
        }
        for (; j < m; j += 2) {
            gadd(__shfl(sidx, j + hf), __shfl(sw, j + hf));
        }
    }

    // merge the two edge halves (fl preserved)
    #pragma unroll
    for (int k = 0; k < 8; k++) acc[k] += __shfl_xor(acc[k], 32);

    if (hf == 0) {
        if constexpr (MODE == 2) {
            const float* xr = xres + (size_t)i * 256 + fl * 8;
            float4 x0 = *(const float4*)xr;
            float4 x1 = *(const float4*)(xr + 4);
            float4 b0 = *(const float4*)(b3 + fl * 8);
            float4 b1 = *(const float4*)(b3 + fl * 8 + 4);
            float4 o0, o1;
            o0.x = acc[0] * di + b0.x + x0.x; o0.y = acc[1] * di + b0.y + x0.y;
            o0.z = acc[2] * di + b0.z + x0.z; o0.w = acc[3] * di + b0.w + x0.w;
            o1.x = acc[4] * di + b1.x + x1.x; o1.y = acc[5] * di + b1.y + x1.y;
            o1.z = acc[6] * di + b1.z + x1.z; o1.w = acc[7] * di + b1.w + x1.w;
            float* yp = Yf + (size_t)i * 256 + fl * 8;
            *(float4*)yp = o0;
            *(float4*)(yp + 4) = o1;
        } else {
            uint4 o;
            o.x = (u32)f2bf(acc[0] * di) | ((u32)f2bf(acc[1] * di) << 16);
            o.y = (u32)f2bf(acc[2] * di) | ((u32)f2bf(acc[3] * di) << 16);
            o.z = (u32)f2bf(acc[4] * di) | ((u32)f2bf(acc[5] * di) << 16);
            o.w = (u32)f2bf(acc[6] * di) | ((u32)f2bf(acc[7] * di) << 16);
            *(uint4*)(Y + (size_t)i * 256 + fl * 8) = o;
        }
    }
}

// ---------------- bf16 MFMA GEMM: C[M][F] = A[M][K] @ Wt[F][K]^T (+bias, +col stats) ----
// 128x128 tile, BK=32, 4 waves each 64x64 (4x4 of 16x16x32 MFMA). C bf16 out.
// Staging via global_load_lds width-16, unpadded LDS [128][32] (round-6 proven).

template <bool STATS, bool BIAS>
__global__ __launch_bounds__(256) void gemm_k(const u16* __restrict__ A, const u16* __restrict__ Wt,
                                              const float* __restrict__ bias, u16* __restrict__ C,
                                              float* __restrict__ colsum, float* __restrict__ colsq,
                                              int M, int K, int F) {
    __shared__ u16 As[128 * 32];
    __shared__ u16 Bs[128 * 32];
    const int m0 = blockIdx.x * 128, f0 = blockIdx.y * 128;
    const int tid = threadIdx.x;
    const int lane = tid & 63, wave = tid >> 6;
    const int waveM = (wave >> 1) * 64, waveN = (wave & 1) * 64;
    const int lrow = tid >> 2, lch = tid & 3;

    f32x4 acc[4][4];
    const f32x4 fz = {0.f, 0.f, 0.f, 0.f};
    #pragma unroll
    for (int i = 0; i < 4; i++)
        #pragma unroll
        for (int j = 0; j < 4; j++) acc[i][j] = fz;

    const int rA0 = m0 + lrow, rA1 = m0 + 64 + lrow;
    const int cA0 = (rA0 < M) ? rA0 : (M - 1);
    const int cA1 = (rA1 < M) ? rA1 : (M - 1);
    const u16* pA0 = A + (size_t)cA0 * K + lch * 8;
    const u16* pA1 = A + (size_t)cA1 * K + lch * 8;
    const u16* pB0 = Wt + (size_t)(f0 + lrow) * K + lch * 8;
    const u16* pB1 = Wt + (size_t)(f0 + 64 + lrow) * K + lch * 8;
    u16* qA0 = &As[tid * 8];
    u16* qA1 = &As[2048 + tid * 8];
    u16* qB0 = &Bs[tid * 8];
    u16* qB1 = &Bs[2048 + tid * 8];

    const int fm = lane & 15, fq = lane >> 4;

    for (int k0 = 0; k0 < K; k0 += 32) {
        __syncthreads();
        glds16(pA0 + k0, qA0);
        glds16(pA1 + k0, qA1);
        glds16(pB0 + k0, qB0);
        glds16(pB1 + k0, qB1);
        __syncthreads();
        bf16x8 af[4], bfr[4];
        #pragma unroll
        for (int i = 0; i < 4; i++)
            af[i] = *(const bf16x8*)&As[(waveM + i * 16 + fm) * 32 + fq * 8];
        #pragma unroll
        for (int j = 0; j < 4; j++)
            bfr[j] = *(const bf16x8*)&Bs[(waveN + j * 16 + fm) * 32 + fq * 8];
        #pragma unroll
        for (int i = 0; i < 4; i++)
            #pragma unroll
            for (int j = 0; j < 4; j++)
                acc[i][j] = __builtin_amdgcn_mfma_f32_16x16x32_bf16(af[i], bfr[j], acc[i][j], 0, 0, 0);
    }

    // C/D layout: col=lane&15, row=(lane>>4)*4+reg  [learn_hip m89/m91]
    #pragma unroll
    for (int j = 0; j < 4; j++) {
        const int col = f0 + waveN + j * 16 + fm;
        const float bcol = BIAS ? bias[col] : 0.f;
        float s = 0.f, s2 = 0.f;
        #pragma unroll
        for (int i = 0; i < 4; i++) {
            const int rb = m0 + waveM + i * 16 + fq * 4;
            #pragma unroll
            for (int r = 0; r < 4; r++) {
                const int row = rb + r;
                if (row < M) {
                    float v = acc[i][j][r] + bcol;
                    C[(size_t)row * F + col] = f2bf(v);
                    if (STATS) { s += v; s2 += v * v; }
                }
            }
        }
        if (STATS) {
            s += __shfl_xor(s, 16);
            s += __shfl_xor(s, 32);
            s2 += __shfl_xor(s2, 16);
            s2 += __shfl_xor(s2, 32);
            if (fq == 0) {
                atomicAdd(&colsum[col], s);
                atomicAdd(&colsq[col], s2);
            }
        }
    }
}

// ---------------- BN(2) + ReLU apply, finalize FOLDED ----------------
// Each block computes the 512 scale/shift values from gemm2's column sums in LDS
// (bnfin2 dispatch removed), then applies in place.

__global__ __launch_bounds__(256) void bnrelu_k(u16* __restrict__ H,
                                                const float* __restrict__ cs, const float* __restrict__ cq,
                                                const float* __restrict__ g, const float* __restrict__ be,
                                                int total) {
    __shared__ float lsc[512], lsh[512];
    const int t = threadIdx.x;
    for (int f = t; f < 512; f += 256) {
        float m = cs[f] * (1.f / NN);
        float v = cq[f] * (1.f / NN) - m * m;
        float s = rsqrtf(v + 1e-5f) * g[f];
        lsc[f] = s;
        lsh[f] = be[f] - m * s;
    }
    __syncthreads();

    int idx = blockIdx.x * 256 + t;
    int base = idx * 8;
    if (base >= total) return;
    uint4 p = *(const uint4*)(H + base);
    int col = base & 511;
    u32 w[4] = {p.x, p.y, p.z, p.w};
    u32 o[4];
    #pragma unroll
    for (int q = 0; q < 4; q++) {
        float x0 = fmaxf(fmaf(bflo(w[q]), lsc[col + 2 * q], lsh[col + 2 * q]), 0.f);
        float x1 = fmaxf(fmaf(bfhi(w[q]), lsc[col + 2 * q + 1], lsh[col + 2 * q + 1]), 0.f);
        o[q] = ((u32)f2bf(x1) << 16) | (u32)f2bf(x0);
    }
    uint4 po = {o[0], o[1], o[2], o[3]};
    *(uint4*)(H + base) = po;
}

// ---------------- launch ----------------

extern "C" void kernel_launch(void* const* d_in, const int* in_sizes, int n_in,
                              void* d_out, int out_size, void* d_ws, size_t ws_size,
                              hipStream_t stream) {
    const float* x   = (const float*)d_in[0];
    const int*   ei  = (const int*)d_in[1];
    const float* W1  = (const float*)d_in[2];
    const float* b1  = (const float*)d_in[3];
    const float* pg1 = (const float*)d_in[4];
    const float* pbe1= (const float*)d_in[5];
    const float* W2  = (const float*)d_in[6];
    const float* b2  = (const float*)d_in[7];
    const float* pg2 = (const float*)d_in[8];
    const float* pbe2= (const float*)d_in[9];
    const float* W3  = (const float*)d_in[10];
    const float* b3  = (const float*)d_in[11];
    float* out = (float*)d_out;

    char* ws = (char*)d_ws;
    size_t off = 0;
    auto alloc = [&](size_t bytes) -> char* {
        char* p = ws + off;
        off += (bytes + 255) & ~(size_t)255;
        return p;
    };
    float* dinv  = (float*)alloc(NN * 4);
    int*   deg   = (int*)alloc(NN * 4);       // deg + stats adjacent -> one memset
    float* stats = (float*)alloc(4 * 512 * 4);
    float* cs1 = stats, *cq1 = stats + 512, *cs2 = stats + 1024, *cq2 = stats + 1536;
    int*   rs    = (int*)alloc(NN * 4);
    int*   cur   = (int*)alloc(NN * 4);
    int*   bsum  = (int*)alloc(256 * 4);
    int*   csr   = (int*)alloc(NE * 4);
    u16*   W1t   = (u16*)alloc((size_t)512 * 256 * 2);
    u16*   W2t   = (u16*)alloc((size_t)512 * 512 * 2);
    u16*   W3t   = (u16*)alloc((size_t)256 * 512 * 2);
    u16*   HB    = (u16*)alloc((size_t)NN * 512 * 2);   // 51.2 MB
    u16*   G3    = (u16*)alloc((size_t)NN * 256 * 2);   // 25.6 MB; doubles as XB (x cast to bf16)

    u16* XB = G3;            // bf16 x — lifetime ends before gemm3 writes G3
    u16* A1 = (u16*)d_out;   // bf16 scratch [N,256] in d_out
    u16* A2 = (u16*)d_out;   // bf16 scratch [N,512] in d_out

    const int* srcp = ei;
    const int* dstp = ei + NE;

    // deg (200192B aligned) + stats (8192B) contiguous -> single memset
    const size_t degAligned = ((size_t)NN * 4 + 255) & ~(size_t)255;
    hipMemsetAsync(deg, 0, degAligned + 4 * 512 * 4, stream);

    const int nbN = (NN + 255) / 256;
    count_k<<<(NE + 255) / 256, 256, 0, stream>>>(dstp, deg, NE);
    scan1_k<<<nbN, 256, 0, stream>>>(deg, dinv, bsum, NN);
    scan2_k<<<1, 256, 0, stream>>>(bsum, nbN);
    scan3_k<<<nbN, 256, 0, stream>>>(deg, bsum, rs, cur, NN);
    fill_k<<<(NE + 255) / 256, 256, 0, stream>>>(srcp, dstp, cur, csr, NE);

    transpose_all_k<<<512, 256, 0, stream>>>(W1, W1t, W2, W2t, W3, W3t);

    cast_k<<<NN * 256 / 8 / 256, 256, 0, stream>>>(x, XB, NN * 256);

    const int MT = (NN + 127) / 128;  // 391
    const int AGB = (NN + 3) / 4;     // wave-per-node agg blocks (4 waves/block)

    // Layer 1: A1 = Agg(XB) [bf16, d_out, edge-paired]; H1 = A1@W1 + b1 -> HB + stats
    aggp_k<0><<<AGB, 256, 0, stream>>>(XB, A1, nullptr, dinv, rs, deg, csr,
                                       nullptr, nullptr);
    gemm_k<true, true><<<dim3(MT, 4), 256, 0, stream>>>(A1, W1t, b1, HB, cs1, cq1, NN, 256, 512);

    // Layer 2: A2 = Agg(relu(bn1(H1))) [bf16, d_out], BN finalize folded, two half-node
    // launches (visibility + no bnfin dispatch); H2 = A2@W2 + b2 -> HB + stats
    agg2_k<<<AGB / 2, 256, 0, stream>>>(HB, A2, dinv, rs, deg, csr, cs1, cq1, pg1, pbe1, 0);
    agg2_k<<<AGB / 2, 256, 0, stream>>>(HB, A2, dinv, rs, deg, csr, cs1, cq1, pg1, pbe1, NN / 2);
    gemm_k<true, true><<<dim3(MT, 4), 256, 0, stream>>>(A2, W2t, b2, HB, cs2, cq2, NN, 512, 512);
    bnrelu_k<<<NN * 512 / 8 / 256, 256, 0, stream>>>(HB, cs2, cq2, pg2, pbe2, NN * 512);

    // Layer 3: G3 = H2@W3 [bf16, ws, overwrites XB]; out = Agg(G3) + b3 + x [f32, edge-paired]
    gemm_k<false, false><<<dim3(MT, 2), 256, 0, stream>>>(HB, W3t, nullptr, G3, nullptr, nullptr, NN, 512, 256);
    aggp_k<2><<<AGB, 256, 0, stream>>>(G3, nullptr, out, dinv, rs, deg, csr,
                                       b3, x);
}

// Round 8
// 681.636 us; speedup vs baseline: 1.6012x; 1.0128x over previous
//
#include <hip/hip_runtime.h>
#include <hip/hip_bf16.h>

#define NN 50000
#define NE 800000

typedef unsigned short u16;
typedef unsigned int   u32;

typedef __attribute__((ext_vector_type(8))) __bf16 bf16x8;
typedef __attribute__((ext_vector_type(4))) float  f32x4;

__device__ __forceinline__ float bf2f(u16 x) {
    u32 u = ((u32)x) << 16;
    return __builtin_bit_cast(float, u);
}
__device__ __forceinline__ u16 f2bf(float f) {
    u32 u = __builtin_bit_cast(u32, f);
    u32 r = (u + 0x7FFFu + ((u >> 16) & 1u)) >> 16;
    return (u16)r;
}
__device__ __forceinline__ float bflo(u32 w) { return __builtin_bit_cast(float, w << 16); }
__device__ __forceinline__ float bfhi(u32 w) { return __builtin_bit_cast(float, w & 0xffff0000u); }

__device__ __forceinline__ int rl_i(int v, int j) {
    return __builtin_amdgcn_readlane(v, j);
}
__device__ __forceinline__ float rl_f(float v, int j) {
    return __builtin_bit_cast(float, __builtin_amdgcn_readlane(__builtin_bit_cast(int, v), j));
}

// async global -> LDS, 16B per lane (HW: wave-uniform LDS base + lane*16; global addr per-lane)
__device__ __forceinline__ void glds16(const u16* g, u16* l) {
    __builtin_amdgcn_global_load_lds((const __attribute__((address_space(1))) void*)g,
                                     (__attribute__((address_space(3))) void*)l, 16, 0, 0);
}

// ---------------- graph preprocessing ----------------

__global__ __launch_bounds__(256) void count_k(const int* __restrict__ dst, int* __restrict__ deg, int E) {
    int e = blockIdx.x * 256 + threadIdx.x;
    if (e < E) atomicAdd(&deg[dst[e]], 1);
}

// scan1 + dinv fused (deg is final here; dinv = rsqrt(deg+1))
__global__ __launch_bounds__(256) void scan1_k(const int* __restrict__ deg, float* __restrict__ dinv,
                                               int* __restrict__ bsum, int n) {
    __shared__ int sd[256];
    int i = blockIdx.x * 256 + threadIdx.x;
    int v = (i < n) ? deg[i] : 0;
    if (i < n) dinv[i] = rsqrtf((float)v + 1.0f);
    sd[threadIdx.x] = v;
    __syncthreads();
    for (int s = 128; s > 0; s >>= 1) {
        if (threadIdx.x < s) sd[threadIdx.x] += sd[threadIdx.x + s];
        __syncthreads();
    }
    if (threadIdx.x == 0) bsum[blockIdx.x] = sd[0];
}

__global__ __launch_bounds__(256) void scan2_k(int* __restrict__ bsum, int nb) {
    __shared__ int sd[256];
    int t = threadIdx.x;
    int v = (t < nb) ? bsum[t] : 0;
    sd[t] = v;
    __syncthreads();
    for (int off = 1; off < 256; off <<= 1) {
        int tv = (t >= off) ? sd[t - off] : 0;
        __syncthreads();
        sd[t] += tv;
        __syncthreads();
    }
    if (t < nb) bsum[t] = sd[t] - v;  // exclusive
}

__global__ __launch_bounds__(256) void scan3_k(const int* __restrict__ deg, const int* __restrict__ bofs,
                                               int* __restrict__ rs, int* __restrict__ cur, int n) {
    __shared__ int sd[256];
    int t = threadIdx.x;
    int i = blockIdx.x * 256 + t;
    int v = (i < n) ? deg[i] : 0;
    sd[t] = v;
    __syncthreads();
    for (int off = 1; off < 256; off <<= 1) {
        int tv = (t >= off) ? sd[t - off] : 0;
        __syncthreads();
        sd[t] += tv;
        __syncthreads();
    }
    int excl = sd[t] - v + bofs[blockIdx.x];
    if (i < n) { rs[i] = excl; cur[i] = excl; }
}

__global__ __launch_bounds__(256) void fill_k(const int* __restrict__ src, const int* __restrict__ dst,
                                              int* __restrict__ cur, int* __restrict__ csr, int E) {
    int e = blockIdx.x * 256 + threadIdx.x;
    if (e < E) {
        int d = dst[e];
        int pos = atomicAdd(&cur[d], 1);
        csr[pos] = src[e];
    }
}

// ---------------- x f32 -> bf16 cast ----------------

__global__ __launch_bounds__(256) void cast_k(const float* __restrict__ X, u16* __restrict__ Y, int total) {
    int idx = (blockIdx.x * 256 + threadIdx.x) * 8;
    if (idx >= total) return;
    float4 a = *(const float4*)(X + idx);
    float4 b = *(const float4*)(X + idx + 4);
    uint4 o;
    o.x = (u32)f2bf(a.x) | ((u32)f2bf(a.y) << 16);
    o.y = (u32)f2bf(a.z) | ((u32)f2bf(a.w) << 16);
    o.z = (u32)f2bf(b.x) | ((u32)f2bf(b.y) << 16);
    o.w = (u32)f2bf(b.z) | ((u32)f2bf(b.w) << 16);
    *(uint4*)(Y + idx) = o;
}

// ---------------- all three weight transposes in ONE launch ----------------
// W f32[K][F] -> Wt bf16[F][K]. 512 blocks: 128 (W1 8x16 tiles) + 256 (W2) + 128 (W3).

__global__ __launch_bounds__(256) void transpose_all_k(const float* __restrict__ W1, u16* __restrict__ W1t,
                                                       const float* __restrict__ W2, u16* __restrict__ W2t,
                                                       const float* __restrict__ W3, u16* __restrict__ W3t) {
    int b = blockIdx.x;
    const float* W; u16* Wt; int K, F, t;
    if (b < 128)      { W = W1; Wt = W1t; K = 256; F = 512; t = b; }
    else if (b < 384) { W = W2; Wt = W2t; K = 512; F = 512; t = b - 128; }
    else              { W = W3; Wt = W3t; K = 512; F = 256; t = b - 384; }
    const int kt = K / 32;
    const int k0 = (t % kt) * 32, f0 = (t / kt) * 32;
    __shared__ float tt[32][33];
    int tx = threadIdx.x & 31, ty = threadIdx.x >> 5;
    for (int r = ty; r < 32; r += 8) tt[r][tx] = W[(size_t)(k0 + r) * F + f0 + tx];
    __syncthreads();
    for (int r = ty; r < 32; r += 8) Wt[(size_t)(f0 + r) * K + k0 + tx] = f2bf(tt[tx][r]);
}

// ---------------- agg2: F=512, wave-per-node, BN-finalize FOLDED ----------------

__global__ __launch_bounds__(256) void agg2_k(const u16* __restrict__ X, u16* __restrict__ Y,
                                              const float* __restrict__ dinv, const int* __restrict__ rs,
                                              const int* __restrict__ dg, const int* __restrict__ csr,
                                              const float* __restrict__ cs, const float* __restrict__ cq,
                                              const float* __restrict__ g, const float* __restrict__ be,
                                              int base) {
    __shared__ float lsc[512], lsh[512];
    const int tid = threadIdx.x;
    for (int f = tid; f < 512; f += 256) {
        float m = cs[f] * (1.f / NN);
        float v = cq[f] * (1.f / NN) - m * m;
        float s = rsqrtf(v + 1e-5f) * g[f];
        lsc[f] = s;
        lsh[f] = be[f] - m * s;
    }
    __syncthreads();

    const int lane = tid & 63;
    const int i = __builtin_amdgcn_readfirstlane(base + blockIdx.x * 4 + (tid >> 6));
    if (i >= NN) return;
    const int start = rs[i], cnt = dg[i];
    const float di = dinv[i];

    float sc[8], sh[8];
    #pragma unroll
    for (int k = 0; k < 8; k++) {
        sc[k] = lsc[lane * 8 + k];
        sh[k] = lsh[lane * 8 + k];
    }

    float acc[8];
    #pragma unroll
    for (int k = 0; k < 8; k++) acc[k] = 0.f;

    auto gadd = [&](int row, float wgt) {
        const u16* p = X + (size_t)row * 512 + lane * 8;
        uint4 q = *(const uint4*)p;
        float v[8];
        v[0] = bflo(q.x); v[1] = bfhi(q.x);
        v[2] = bflo(q.y); v[3] = bfhi(q.y);
        v[4] = bflo(q.z); v[5] = bfhi(q.z);
        v[6] = bflo(q.w); v[7] = bfhi(q.w);
        #pragma unroll
        for (int k = 0; k < 8; k++) {
            float x = fmaxf(fmaf(v[k], sc[k], sh[k]), 0.f);
            acc[k] = fmaf(x, wgt, acc[k]);
        }
    };

    gadd(i, di);  // self-loop term

    for (int bse = 0; bse < cnt; bse += 64) {
        const int m = min(64, cnt - bse);
        int   sidx = 0;
        float sw   = 0.f;
        if (lane < m) {
            sidx = csr[start + bse + lane];
            sw   = dinv[sidx];
        }
        int j = 0;
        for (; j + 8 <= m; j += 8) {
            int   r[8];
            float w[8];
            #pragma unroll
            for (int q = 0; q < 8; q++) {
                r[q] = rl_i(sidx, j + q);
                w[q] = rl_f(sw, j + q);
            }
            #pragma unroll
            for (int q = 0; q < 8; q++) gadd(r[q], w[q]);
        }
        for (; j < m; j++) gadd(rl_i(sidx, j), rl_f(sw, j));
    }

    uint4 o;
    o.x = (u32)f2bf(acc[0] * di) | ((u32)f2bf(acc[1] * di) << 16);
    o.y = (u32)f2bf(acc[2] * di) | ((u32)f2bf(acc[3] * di) << 16);
    o.z = (u32)f2bf(acc[4] * di) | ((u32)f2bf(acc[5] * di) << 16);
    o.w = (u32)f2bf(acc[6] * di) | ((u32)f2bf(acc[7] * di) << 16);
    *(uint4*)(Y + (size_t)i * 512 + lane * 8) = o;
}

// ---------------- GCN aggregation, F=256, EDGE-PAIRED (round-5/6 proven) -------

template <int MODE>
__global__ __launch_bounds__(256) void aggp_k(const u16* __restrict__ X, u16* __restrict__ Y,
                                              float* __restrict__ Yf,
                                              const float* __restrict__ dinv, const int* __restrict__ rs,
                                              const int* __restrict__ dg, const int* __restrict__ csr,
                                              const float* __restrict__ b3, const float* __restrict__ xres) {
    const int tid  = threadIdx.x;
    const int lane = tid & 63;
    const int hf   = lane >> 5;   // edge-pair half 0/1
    const int fl   = lane & 31;   // feat block: covers feats fl*8 .. fl*8+7
    const int i = blockIdx.x * 4 + (tid >> 6);  // one wave per node
    if (i >= NN) return;
    const int start = rs[i], cnt = dg[i];
    const float di = dinv[i];

    float acc[8];
    #pragma unroll
    for (int k = 0; k < 8; k++) acc[k] = 0.f;

    auto gadd = [&](int row, float wgt) {
        uint4 q = *(const uint4*)(X + (size_t)row * 256 + fl * 8);
        float v[8];
        v[0] = bflo(q.x); v[1] = bfhi(q.x);
        v[2] = bflo(q.y); v[3] = bfhi(q.y);
        v[4] = bflo(q.z); v[5] = bfhi(q.z);
        v[6] = bflo(q.w); v[7] = bfhi(q.w);
        #pragma unroll
        for (int k = 0; k < 8; k++) acc[k] = fmaf(v[k], wgt, acc[k]);
    };

    // self-loop: lower half contributes di, upper half 0 (counted once after merge)
    gadd(i, hf ? 0.f : di);

    for (int bse = 0; bse < cnt; bse += 64) {
        const int m = min(64, cnt - bse);
        int   sidx = 0;
        float sw   = 0.f;   // lanes >= m keep (row 0, weight 0): zero contribution
        if (lane < m) {
            sidx = csr[start + bse + lane];
            sw   = dinv[sidx];
        }
        int j = 0;
        for (; j + 8 <= m; j += 8) {
            int   r0 = __shfl(sidx, j + 0 + hf), r1 = __shfl(sidx, j + 2 + hf);
            int   r2 = __shfl(sidx, j + 4 + hf), r3 = __shfl(sidx, j + 6 + hf);
            float w0 = __shfl(sw, j + 0 + hf), w1 = __shfl(sw, j + 2 + hf);
            float w2 = __shfl(sw, j + 4 + hf), w3 = __shfl(sw, j + 6 + hf);
            gadd(r0, w0);
            gadd(r1, w1);
            gadd(r2, w2);
            gadd(r3, w3);
        }
        for (; j < m; j += 2) {
            gadd(__shfl(sidx, j + hf), __shfl(sw, j + hf));
        }
    }

    // merge the two edge halves (fl preserved)
    #pragma unroll
    for (int k = 0; k < 8; k++) acc[k] += __shfl_xor(acc[k], 32);

    if (hf == 0) {
        if constexpr (MODE == 2) {
            const float* xr = xres + (size_t)i * 256 + fl * 8;
            float4 x0 = *(const float4*)xr;
            float4 x1 = *(const float4*)(xr + 4);
            float4 b0 = *(const float4*)(b3 + fl * 8);
            float4 b1 = *(const float4*)(b3 + fl * 8 + 4);
            float4 o0, o1;
            o0.x = acc[0] * di + b0.x + x0.x; o0.y = acc[1] * di + b0.y + x0.y;
            o0.z = acc[2] * di + b0.z + x0.z; o0.w = acc[3] * di + b0.w + x0.w;
            o1.x = acc[4] * di + b1.x + x1.x; o1.y = acc[5] * di + b1.y + x1.y;
            o1.z = acc[6] * di + b1.z + x1.z; o1.w = acc[7] * di + b1.w + x1.w;
            float* yp = Yf + (size_t)i * 256 + fl * 8;
            *(float4*)yp = o0;
            *(float4*)(yp + 4) = o1;
        } else {
            uint4 o;
            o.x = (u32)f2bf(acc[0] * di) | ((u32)f2bf(acc[1] * di) << 16);
            o.y = (u32)f2bf(acc[2] * di) | ((u32)f2bf(acc[3] * di) << 16);
            o.z = (u32)f2bf(acc[4] * di) | ((u32)f2bf(acc[5] * di) << 16);
            o.w = (u32)f2bf(acc[6] * di) | ((u32)f2bf(acc[7] * di) << 16);
            *(uint4*)(Y + (size_t)i * 256 + fl * 8) = o;
        }
    }
}

// ---------------- bf16 MFMA GEMM: C[M][F] = A[M][K] @ Wt[F][K]^T (+bias, +col stats) ----
// 128x128 tile, BK=32, 4 waves each 64x64 (4x4 of 16x16x32 MFMA). C bf16 out.
// Staging via global_load_lds width-16 into UNPADDED [128][32] LDS.
//
// ROUND 8: XOR bank-swizzle (rule #21: both-sides-or-neither with glds).
// Problem: linear layout reads fragment rows at byte row*64 -> access-phase lanes
// 0-15 (fq=0, fm=0..15) hit only 2 bank-spans (8-way conflict, 3.2M cycles measured).
// Fix: LDS chunk position pos = fq ^ ((row>>1)&3).
//   - glds dest stays linear (required); thread tid (slot row=tid>>2, pos=tid&3)
//     loads GLOBAL chunk (tid&3)^((tid>>3)&3)   [source pre-swizzle, per-lane legal]
//   - fragment read uses chunk index fq ^ ((fm>>1)&3)  [same involution]
// Post-swizzle each 16-lane phase spreads over 8 spans x 2 lanes -> 2-way = free.

template <bool STATS, bool BIAS>
__global__ __launch_bounds__(256) void gemm_k(const u16* __restrict__ A, const u16* __restrict__ Wt,
                                              const float* __restrict__ bias, u16* __restrict__ C,
                                              float* __restrict__ colsum, float* __restrict__ colsq,
                                              int M, int K, int F) {
    __shared__ u16 As[128 * 32];
    __shared__ u16 Bs[128 * 32];
    const int m0 = blockIdx.x * 128, f0 = blockIdx.y * 128;
    const int tid = threadIdx.x;
    const int lane = tid & 63, wave = tid >> 6;
    const int waveM = (wave >> 1) * 64, waveN = (wave & 1) * 64;
    const int lrow = tid >> 2;
    const int lch  = (tid & 3) ^ ((tid >> 3) & 3);   // pre-swizzled global chunk

    f32x4 acc[4][4];
    const f32x4 fz = {0.f, 0.f, 0.f, 0.f};
    #pragma unroll
    for (int i = 0; i < 4; i++)
        #pragma unroll
        for (int j = 0; j < 4; j++) acc[i][j] = fz;

    const int rA0 = m0 + lrow, rA1 = m0 + 64 + lrow;
    const int cA0 = (rA0 < M) ? rA0 : (M - 1);
    const int cA1 = (rA1 < M) ? rA1 : (M - 1);
    const u16* pA0 = A + (size_t)cA0 * K + lch * 8;
    const u16* pA1 = A + (size_t)cA1 * K + lch * 8;
    const u16* pB0 = Wt + (size_t)(f0 + lrow) * K + lch * 8;
    const u16* pB1 = Wt + (size_t)(f0 + 64 + lrow) * K + lch * 8;
    u16* qA0 = &As[tid * 8];
    u16* qA1 = &As[2048 + tid * 8];
    u16* qB0 = &Bs[tid * 8];
    u16* qB1 = &Bs[2048 + tid * 8];

    const int fm = lane & 15, fq = lane >> 4;
    const int fqs = fq ^ ((fm >> 1) & 3);            // swizzled read chunk

    for (int k0 = 0; k0 < K; k0 += 32) {
        __syncthreads();
        glds16(pA0 + k0, qA0);
        glds16(pA1 + k0, qA1);
        glds16(pB0 + k0, qB0);
        glds16(pB1 + k0, qB1);
        __syncthreads();
        bf16x8 af[4], bfr[4];
        #pragma unroll
        for (int i = 0; i < 4; i++)
            af[i] = *(const bf16x8*)&As[(waveM + i * 16 + fm) * 32 + fqs * 8];
        #pragma unroll
        for (int j = 0; j < 4; j++)
            bfr[j] = *(const bf16x8*)&Bs[(waveN + j * 16 + fm) * 32 + fqs * 8];
        #pragma unroll
        for (int i = 0; i < 4; i++)
            #pragma unroll
            for (int j = 0; j < 4; j++)
                acc[i][j] = __builtin_amdgcn_mfma_f32_16x16x32_bf16(af[i], bfr[j], acc[i][j], 0, 0, 0);
    }

    // C/D layout: col=lane&15, row=(lane>>4)*4+reg  [learn_hip m89/m91]
    #pragma unroll
    for (int j = 0; j < 4; j++) {
        const int col = f0 + waveN + j * 16 + fm;
        const float bcol = BIAS ? bias[col] : 0.f;
        float s = 0.f, s2 = 0.f;
        #pragma unroll
        for (int i = 0; i < 4; i++) {
            const int rb = m0 + waveM + i * 16 + fq * 4;
            #pragma unroll
            for (int r = 0; r < 4; r++) {
                const int row = rb + r;
                if (row < M) {
                    float v = acc[i][j][r] + bcol;
                    C[(size_t)row * F + col] = f2bf(v);
                    if (STATS) { s += v; s2 += v * v; }
                }
            }
        }
        if (STATS) {
            s += __shfl_xor(s, 16);
            s += __shfl_xor(s, 32);
            s2 += __shfl_xor(s2, 16);
            s2 += __shfl_xor(s2, 32);
            if (fq == 0) {
                atomicAdd(&colsum[col], s);
                atomicAdd(&colsq[col], s2);
            }
        }
    }
}

// ---------------- BN(2) + ReLU apply, finalize FOLDED ----------------

__global__ __launch_bounds__(256) void bnrelu_k(u16* __restrict__ H,
                                                const float* __restrict__ cs, const float* __restrict__ cq,
                                                const float* __restrict__ g, const float* __restrict__ be,
                                                int total) {
    __shared__ float lsc[512], lsh[512];
    const int t = threadIdx.x;
    for (int f = t; f < 512; f += 256) {
        float m = cs[f] * (1.f / NN);
        float v = cq[f] * (1.f / NN) - m * m;
        float s = rsqrtf(v + 1e-5f) * g[f];
        lsc[f] = s;
        lsh[f] = be[f] - m * s;
    }
    __syncthreads();

    int idx = blockIdx.x * 256 + t;
    int base = idx * 8;
    if (base >= total) return;
    uint4 p = *(const uint4*)(H + base);
    int col = base & 511;
    u32 w[4] = {p.x, p.y, p.z, p.w};
    u32 o[4];
    #pragma unroll
    for (int q = 0; q < 4; q++) {
        float x0 = fmaxf(fmaf(bflo(w[q]), lsc[col + 2 * q], lsh[col + 2 * q]), 0.f);
        float x1 = fmaxf(fmaf(bfhi(w[q]), lsc[col + 2 * q + 1], lsh[col + 2 * q + 1]), 0.f);
        o[q] = ((u32)f2bf(x1) << 16) | (u32)f2bf(x0);
    }
    uint4 po = {o[0], o[1], o[2], o[3]};
    *(uint4*)(H + base) = po;
}

// ---------------- launch ----------------

extern "C" void kernel_launch(void* const* d_in, const int* in_sizes, int n_in,
                              void* d_out, int out_size, void* d_ws, size_t ws_size,
                              hipStream_t stream) {
    const float* x   = (const float*)d_in[0];
    const int*   ei  = (const int*)d_in[1];
    const float* W1  = (const float*)d_in[2];
    const float* b1  = (const float*)d_in[3];
    const float* pg1 = (const float*)d_in[4];
    const float* pbe1= (const float*)d_in[5];
    const float* W2  = (const float*)d_in[6];
    const float* b2  = (const float*)d_in[7];
    const float* pg2 = (const float*)d_in[8];
    const float* pbe2= (const float*)d_in[9];
    const float* W3  = (const float*)d_in[10];
    const float* b3  = (const float*)d_in[11];
    float* out = (float*)d_out;

    char* ws = (char*)d_ws;
    size_t off = 0;
    auto alloc = [&](size_t bytes) -> char* {
        char* p = ws + off;
        off += (bytes + 255) & ~(size_t)255;
        return p;
    };
    float* dinv  = (float*)alloc(NN * 4);
    int*   deg   = (int*)alloc(NN * 4);       // deg + stats adjacent -> one memset
    float* stats = (float*)alloc(4 * 512 * 4);
    float* cs1 = stats, *cq1 = stats + 512, *cs2 = stats + 1024, *cq2 = stats + 1536;
    int*   rs    = (int*)alloc(NN * 4);
    int*   cur   = (int*)alloc(NN * 4);
    int*   bsum  = (int*)alloc(256 * 4);
    int*   csr   = (int*)alloc(NE * 4);
    u16*   W1t   = (u16*)alloc((size_t)512 * 256 * 2);
    u16*   W2t   = (u16*)alloc((size_t)512 * 512 * 2);
    u16*   W3t   = (u16*)alloc((size_t)256 * 512 * 2);
    u16*   HB    = (u16*)alloc((size_t)NN * 512 * 2);   // 51.2 MB
    u16*   G3    = (u16*)alloc((size_t)NN * 256 * 2);   // 25.6 MB; doubles as XB (x cast to bf16)

    u16* XB = G3;            // bf16 x — lifetime ends before gemm3 writes G3
    u16* A1 = (u16*)d_out;   // bf16 scratch [N,256] in d_out
    u16* A2 = (u16*)d_out;   // bf16 scratch [N,512] in d_out

    const int* srcp = ei;
    const int* dstp = ei + NE;

    // deg (200192B aligned) + stats (8192B) contiguous -> single memset
    const size_t degAligned = ((size_t)NN * 4 + 255) & ~(size_t)255;
    hipMemsetAsync(deg, 0, degAligned + 4 * 512 * 4, stream);

    const int nbN = (NN + 255) / 256;
    count_k<<<(NE + 255) / 256, 256, 0, stream>>>(dstp, deg, NE);
    scan1_k<<<nbN, 256, 0, stream>>>(deg, dinv, bsum, NN);
    scan2_k<<<1, 256, 0, stream>>>(bsum, nbN);
    scan3_k<<<nbN, 256, 0, stream>>>(deg, bsum, rs, cur, NN);
    fill_k<<<(NE + 255) / 256, 256, 0, stream>>>(srcp, dstp, cur, csr, NE);

    transpose_all_k<<<512, 256, 0, stream>>>(W1, W1t, W2, W2t, W3, W3t);

    cast_k<<<NN * 256 / 8 / 256, 256, 0, stream>>>(x, XB, NN * 256);

    const int MT = (NN + 127) / 128;  // 391
    const int AGB = (NN + 3) / 4;     // wave-per-node agg blocks (4 waves/block)

    // Layer 1: A1 = Agg(XB) [bf16, d_out, edge-paired]; H1 = A1@W1 + b1 -> HB + stats
    aggp_k<0><<<AGB, 256, 0, stream>>>(XB, A1, nullptr, dinv, rs, deg, csr,
                                       nullptr, nullptr);
    gemm_k<true, true><<<dim3(MT, 4), 256, 0, stream>>>(A1, W1t, b1, HB, cs1, cq1, NN, 256, 512);

    // Layer 2: A2 = Agg(relu(bn1(H1))) [bf16, d_out], BN finalize folded, two half-node
    // launches; H2 = A2@W2 + b2 -> HB + stats
    agg2_k<<<AGB / 2, 256, 0, stream>>>(HB, A2, dinv, rs, deg, csr, cs1, cq1, pg1, pbe1, 0);
    agg2_k<<<AGB / 2, 256, 0, stream>>>(HB, A2, dinv, rs, deg, csr, cs1, cq1, pg1, pbe1, NN / 2);
    gemm_k<true, true><<<dim3(MT, 4), 256, 0, stream>>>(A2, W2t, b2, HB, cs2, cq2, NN, 512, 512);
    bnrelu_k<<<NN * 512 / 8 / 256, 256, 0, stream>>>(HB, cs2, cq2, pg2, pbe2, NN * 512);

    // Layer 3: G3 = H2@W3 [bf16, ws, overwrites XB]; out = Agg(G3) + b3 + x [f32, edge-paired]
    gemm_k<false, false><<<dim3(MT, 2), 256, 0, stream>>>(HB, W3t, nullptr, G3, nullptr, nullptr, NN, 512, 256);
    aggp_k<2><<<AGB, 256, 0, stream>>>(G3, nullptr, out, dinv, rs, deg, csr,
                                       b3, x);
}

// Round 9
// 654.844 us; speedup vs baseline: 1.6667x; 1.0409x over previous
//
#include <hip/hip_runtime.h>
#include <hip/hip_bf16.h>

#define NN 50000
#define NE 800000

typedef unsigned short u16;
typedef unsigned int   u32;

typedef __attribute__((ext_vector_type(8))) __bf16 bf16x8;
typedef __attribute__((ext_vector_type(4))) float  f32x4;

__device__ __forceinline__ float bf2f(u16 x) {
    u32 u = ((u32)x) << 16;
    return __builtin_bit_cast(float, u);
}
__device__ __forceinline__ u16 f2bf(float f) {
    u32 u = __builtin_bit_cast(u32, f);
    u32 r = (u + 0x7FFFu + ((u >> 16) & 1u)) >> 16;
    return (u16)r;
}
__device__ __forceinline__ float bflo(u32 w) { return __builtin_bit_cast(float, w << 16); }
__device__ __forceinline__ float bfhi(u32 w) { return __builtin_bit_cast(float, w & 0xffff0000u); }

__device__ __forceinline__ int rl_i(int v, int j) {
    return __builtin_amdgcn_readlane(v, j);
}
__device__ __forceinline__ float rl_f(float v, int j) {
    return __builtin_bit_cast(float, __builtin_amdgcn_readlane(__builtin_bit_cast(int, v), j));
}

// async global -> LDS, 16B per lane (HW: wave-uniform LDS base + lane*16; global addr per-lane)
__device__ __forceinline__ void glds16(const u16* g, u16* l) {
    __builtin_amdgcn_global_load_lds((const __attribute__((address_space(1))) void*)g,
                                     (__attribute__((address_space(3))) void*)l, 16, 0, 0);
}

// ---------------- graph preprocessing ----------------

__global__ __launch_bounds__(256) void count_k(const int* __restrict__ dst, int* __restrict__ deg, int E) {
    int e = blockIdx.x * 256 + threadIdx.x;
    if (e < E) atomicAdd(&deg[dst[e]], 1);
}

// scan1 + dinv fused (deg is final here; dinv = rsqrt(deg+1))
__global__ __launch_bounds__(256) void scan1_k(const int* __restrict__ deg, float* __restrict__ dinv,
                                               int* __restrict__ bsum, int n) {
    __shared__ int sd[256];
    int i = blockIdx.x * 256 + threadIdx.x;
    int v = (i < n) ? deg[i] : 0;
    if (i < n) dinv[i] = rsqrtf((float)v + 1.0f);
    sd[threadIdx.x] = v;
    __syncthreads();
    for (int s = 128; s > 0; s >>= 1) {
        if (threadIdx.x < s) sd[threadIdx.x] += sd[threadIdx.x + s];
        __syncthreads();
    }
    if (threadIdx.x == 0) bsum[blockIdx.x] = sd[0];
}

__global__ __launch_bounds__(256) void scan2_k(int* __restrict__ bsum, int nb) {
    __shared__ int sd[256];
    int t = threadIdx.x;
    int v = (t < nb) ? bsum[t] : 0;
    sd[t] = v;
    __syncthreads();
    for (int off = 1; off < 256; off <<= 1) {
        int tv = (t >= off) ? sd[t - off] : 0;
        __syncthreads();
        sd[t] += tv;
        __syncthreads();
    }
    if (t < nb) bsum[t] = sd[t] - v;  // exclusive
}

__global__ __launch_bounds__(256) void scan3_k(const int* __restrict__ deg, const int* __restrict__ bofs,
                                               int* __restrict__ rs, int* __restrict__ cur, int n) {
    __shared__ int sd[256];
    int t = threadIdx.x;
    int i = blockIdx.x * 256 + t;
    int v = (i < n) ? deg[i] : 0;
    sd[t] = v;
    __syncthreads();
    for (int off = 1; off < 256; off <<= 1) {
        int tv = (t >= off) ? sd[t - off] : 0;
        __syncthreads();
        sd[t] += tv;
        __syncthreads();
    }
    int excl = sd[t] - v + bofs[blockIdx.x];
    if (i < n) { rs[i] = excl; cur[i] = excl; }
}

__global__ __launch_bounds__(256) void fill_k(const int* __restrict__ src, const int* __restrict__ dst,
                                              int* __restrict__ cur, int* __restrict__ csr, int E) {
    int e = blockIdx.x * 256 + threadIdx.x;
    if (e < E) {
        int d = dst[e];
        int pos = atomicAdd(&cur[d], 1);
        csr[pos] = src[e];
    }
}

// ---------------- x f32 -> bf16 cast ----------------

__global__ __launch_bounds__(256) void cast_k(const float* __restrict__ X, u16* __restrict__ Y, int total) {
    int idx = (blockIdx.x * 256 + threadIdx.x) * 8;
    if (idx >= total) return;
    float4 a = *(const float4*)(X + idx);
    float4 b = *(const float4*)(X + idx + 4);
    uint4 o;
    o.x = (u32)f2bf(a.x) | ((u32)f2bf(a.y) << 16);
    o.y = (u32)f2bf(a.z) | ((u32)f2bf(a.w) << 16);
    o.z = (u32)f2bf(b.x) | ((u32)f2bf(b.y) << 16);
    o.w = (u32)f2bf(b.z) | ((u32)f2bf(b.w) << 16);
    *(uint4*)(Y + idx) = o;
}

// ---------------- all three weight transposes in ONE launch ----------------
// W f32[K][F] -> Wt bf16[F][K]. 512 blocks: 128 (W1 8x16 tiles) + 256 (W2) + 128 (W3).

__global__ __launch_bounds__(256) void transpose_all_k(const float* __restrict__ W1, u16* __restrict__ W1t,
                                                       const float* __restrict__ W2, u16* __restrict__ W2t,
                                                       const float* __restrict__ W3, u16* __restrict__ W3t) {
    int b = blockIdx.x;
    const float* W; u16* Wt; int K, F, t;
    if (b < 128)      { W = W1; Wt = W1t; K = 256; F = 512; t = b; }
    else if (b < 384) { W = W2; Wt = W2t; K = 512; F = 512; t = b - 128; }
    else              { W = W3; Wt = W3t; K = 512; F = 256; t = b - 384; }
    const int kt = K / 32;
    const int k0 = (t % kt) * 32, f0 = (t / kt) * 32;
    __shared__ float tt[32][33];
    int tx = threadIdx.x & 31, ty = threadIdx.x >> 5;
    for (int r = ty; r < 32; r += 8) tt[r][tx] = W[(size_t)(k0 + r) * F + f0 + tx];
    __syncthreads();
    for (int r = ty; r < 32; r += 8) Wt[(size_t)(f0 + r) * K + k0 + tx] = f2bf(tt[tx][r]);
}

// ---------------- agg2: F=512, wave-per-node, BN-finalize FOLDED ----------------

__global__ __launch_bounds__(256) void agg2_k(const u16* __restrict__ X, u16* __restrict__ Y,
                                              const float* __restrict__ dinv, const int* __restrict__ rs,
                                              const int* __restrict__ dg, const int* __restrict__ csr,
                                              const float* __restrict__ cs, const float* __restrict__ cq,
                                              const float* __restrict__ g, const float* __restrict__ be,
                                              int base) {
    __shared__ float lsc[512], lsh[512];
    const int tid = threadIdx.x;
    for (int f = tid; f < 512; f += 256) {
        float m = cs[f] * (1.f / NN);
        float v = cq[f] * (1.f / NN) - m * m;
        float s = rsqrtf(v + 1e-5f) * g[f];
        lsc[f] = s;
        lsh[f] = be[f] - m * s;
    }
    __syncthreads();

    const int lane = tid & 63;
    const int i = __builtin_amdgcn_readfirstlane(base + blockIdx.x * 4 + (tid >> 6));
    if (i >= NN) return;
    const int start = rs[i], cnt = dg[i];
    const float di = dinv[i];

    float sc[8], sh[8];
    #pragma unroll
    for (int k = 0; k < 8; k++) {
        sc[k] = lsc[lane * 8 + k];
        sh[k] = lsh[lane * 8 + k];
    }

    float acc[8];
    #pragma unroll
    for (int k = 0; k < 8; k++) acc[k] = 0.f;

    auto gadd = [&](int row, float wgt) {
        const u16* p = X + (size_t)row * 512 + lane * 8;
        uint4 q = *(const uint4*)p;
        float v[8];
        v[0] = bflo(q.x); v[1] = bfhi(q.x);
        v[2] = bflo(q.y); v[3] = bfhi(q.y);
        v[4] = bflo(q.z); v[5] = bfhi(q.z);
        v[6] = bflo(q.w); v[7] = bfhi(q.w);
        #pragma unroll
        for (int k = 0; k < 8; k++) {
            float x = fmaxf(fmaf(v[k], sc[k], sh[k]), 0.f);
            acc[k] = fmaf(x, wgt, acc[k]);
        }
    };

    gadd(i, di);  // self-loop term

    for (int bse = 0; bse < cnt; bse += 64) {
        const int m = min(64, cnt - bse);
        int   sidx = 0;
        float sw   = 0.f;
        if (lane < m) {
            sidx = csr[start + bse + lane];
            sw   = dinv[sidx];
        }
        int j = 0;
        for (; j + 8 <= m; j += 8) {
            int   r[8];
            float w[8];
            #pragma unroll
            for (int q = 0; q < 8; q++) {
                r[q] = rl_i(sidx, j + q);
                w[q] = rl_f(sw, j + q);
            }
            #pragma unroll
            for (int q = 0; q < 8; q++) gadd(r[q], w[q]);
        }
        for (; j < m; j++) gadd(rl_i(sidx, j), rl_f(sw, j));
    }

    uint4 o;
    o.x = (u32)f2bf(acc[0] * di) | ((u32)f2bf(acc[1] * di) << 16);
    o.y = (u32)f2bf(acc[2] * di) | ((u32)f2bf(acc[3] * di) << 16);
    o.z = (u32)f2bf(acc[4] * di) | ((u32)f2bf(acc[5] * di) << 16);
    o.w = (u32)f2bf(acc[6] * di) | ((u32)f2bf(acc[7] * di) << 16);
    *(uint4*)(Y + (size_t)i * 512 + lane * 8) = o;
}

// ---------------- GCN aggregation, F=256, EDGE-PAIRED (round-5/6 proven) -------

template <int MODE>
__global__ __launch_bounds__(256) void aggp_k(const u16* __restrict__ X, u16* __restrict__ Y,
                                              float* __restrict__ Yf,
                                              const float* __restrict__ dinv, const int* __restrict__ rs,
                                              const int* __restrict__ dg, const int* __restrict__ csr,
                                              const float* __restrict__ b3, const float* __restrict__ xres) {
    const int tid  = threadIdx.x;
    const int lane = tid & 63;
    const int hf   = lane >> 5;   // edge-pair half 0/1
    const int fl   = lane & 31;   // feat block: covers feats fl*8 .. fl*8+7
    const int i = blockIdx.x * 4 + (tid >> 6);  // one wave per node
    if (i >= NN) return;
    const int start = rs[i], cnt = dg[i];
    const float di = dinv[i];

    float acc[8];
    #pragma unroll
    for (int k = 0; k < 8; k++) acc[k] = 0.f;

    auto gadd = [&](int row, float wgt) {
        uint4 q = *(const uint4*)(X + (size_t)row * 256 + fl * 8);
        float v[8];
        v[0] = bflo(q.x); v[1] = bfhi(q.x);
        v[2] = bflo(q.y); v[3] = bfhi(q.y);
        v[4] = bflo(q.z); v[5] = bfhi(q.z);
        v[6] = bflo(q.w); v[7] = bfhi(q.w);
        #pragma unroll
        for (int k = 0; k < 8; k++) acc[k] = fmaf(v[k], wgt, acc[k]);
    };

    // self-loop: lower half contributes di, upper half 0 (counted once after merge)
    gadd(i, hf ? 0.f : di);

    for (int bse = 0; bse < cnt; bse += 64) {
        const int m = min(64, cnt - bse);
        int   sidx = 0;
        float sw   = 0.f;   // lanes >= m keep (row 0, weight 0): zero contribution
        if (lane < m) {
            sidx = csr[start + bse + lane];
            sw   = dinv[sidx];
        }
        int j = 0;
        for (; j + 8 <= m; j += 8) {
            int   r0 = __shfl(sidx, j + 0 + hf), r1 = __shfl(sidx, j + 2 + hf);
            int   r2 = __shfl(sidx, j + 4 + hf), r3 = __shfl(sidx, j + 6 + hf);
            float w0 = __shfl(sw, j + 0 + hf), w1 = __shfl(sw, j + 2 + hf);
            float w2 = __shfl(sw, j + 4 + hf), w3 = __shfl(sw, j + 6 + hf);
            gadd(r0, w0);
            gadd(r1, w1);
            gadd(r2, w2);
            gadd(r3, w3);
        }
        for (; j < m; j += 2) {
            gadd(__shfl(sidx, j + hf), __shfl(sw, j + hf));
        }
    }

    // merge the two edge halves (fl preserved)
    #pragma unroll
    for (int k = 0; k < 8; k++) acc[k] += __shfl_xor(acc[k], 32);

    if (hf == 0) {
        if constexpr (MODE == 2) {
            const float* xr = xres + (size_t)i * 256 + fl * 8;
            float4 x0 = *(const float4*)xr;
            float4 x1 = *(const float4*)(xr + 4);
            float4 b0 = *(const float4*)(b3 + fl * 8);
            float4 b1 = *(const float4*)(b3 + fl * 8 + 4);
            float4 o0, o1;
            o0.x = acc[0] * di + b0.x + x0.x; o0.y = acc[1] * di + b0.y + x0.y;
            o0.z = acc[2] * di + b0.z + x0.z; o0.w = acc[3] * di + b0.w + x0.w;
            o1.x = acc[4] * di + b1.x + x1.x; o1.y = acc[5] * di + b1.y + x1.y;
            o1.z = acc[6] * di + b1.z + x1.z; o1.w = acc[7] * di + b1.w + x1.w;
            float* yp = Yf + (size_t)i * 256 + fl * 8;
            *(float4*)yp = o0;
            *(float4*)(yp + 4) = o1;
        } else {
            uint4 o;
            o.x = (u32)f2bf(acc[0] * di) | ((u32)f2bf(acc[1] * di) << 16);
            o.y = (u32)f2bf(acc[2] * di) | ((u32)f2bf(acc[3] * di) << 16);
            o.z = (u32)f2bf(acc[4] * di) | ((u32)f2bf(acc[5] * di) << 16);
            o.w = (u32)f2bf(acc[6] * di) | ((u32)f2bf(acc[7] * di) << 16);
            *(uint4*)(Y + (size_t)i * 256 + fl * 8) = o;
        }
    }
}

// ---------------- bf16 MFMA GEMM: C[M][F] = A[M][K] @ Wt[F][K]^T (+bias, +col stats) ----
// 128x128 tile, BK=32, 4 waves each 64x64 (4x4 of 16x16x32 MFMA). C bf16 out.
// glds width-16 into UNPADDED [128][32] LDS; XOR bank-swizzle (round-8, conflicts = 0).
//
// ROUND 9 (T3/T4): TRIPLE-BUFFERED K-loop with COUNTED vmcnt + raw s_barrier.
// Round-8 PMC showed ~2400 cyc/K-step vs ~180 of compute: the vmcnt(0) drain that
// __syncthreads() implies serialized every step on full L3/HBM latency. Now tiles
// t+1, t+2 stay in flight across barriers (vmcnt(8) steady state, never 0 mid-loop).
// Buffer safety: stage target at iter t = read buffer of iter t-1, whose reads
// completed before t-1's end barrier. Grid is (F-tiles, M-tiles): x fastest ->
// the 4 sibling blocks sharing an A-panel dispatch adjacently (A fetched ~once).

template <bool STATS, bool BIAS>
__global__ __launch_bounds__(256) void gemm_k(const u16* __restrict__ A, const u16* __restrict__ Wt,
                                              const float* __restrict__ bias, u16* __restrict__ C,
                                              float* __restrict__ colsum, float* __restrict__ colsq,
                                              int M, int K, int F) {
    __shared__ u16 As[3][128 * 32];
    __shared__ u16 Bs[3][128 * 32];
    const int f0 = blockIdx.x * 128, m0 = blockIdx.y * 128;   // x = F-tile (fast-varying)
    const int tid = threadIdx.x;
    const int lane = tid & 63, wave = tid >> 6;
    const int waveM = (wave >> 1) * 64, waveN = (wave & 1) * 64;
    const int lrow = tid >> 2;
    const int lch  = (tid & 3) ^ ((tid >> 3) & 3);   // pre-swizzled global chunk

    f32x4 acc[4][4];
    const f32x4 fz = {0.f, 0.f, 0.f, 0.f};
    #pragma unroll
    for (int i = 0; i < 4; i++)
        #pragma unroll
        for (int j = 0; j < 4; j++) acc[i][j] = fz;

    const int rA0 = m0 + lrow, rA1 = m0 + 64 + lrow;
    const int cA0 = (rA0 < M) ? rA0 : (M - 1);
    const int cA1 = (rA1 < M) ? rA1 : (M - 1);
    const u16* pA0 = A + (size_t)cA0 * K + lch * 8;
    const u16* pA1 = A + (size_t)cA1 * K + lch * 8;
    const u16* pB0 = Wt + (size_t)(f0 + lrow) * K + lch * 8;
    const u16* pB1 = Wt + (size_t)(f0 + 64 + lrow) * K + lch * 8;

    auto stage = [&](int tile, int buf) {
        const int k0 = tile * 32;
        glds16(pA0 + k0, &As[buf][tid * 8]);
        glds16(pA1 + k0, &As[buf][2048 + tid * 8]);
        glds16(pB0 + k0, &Bs[buf][tid * 8]);
        glds16(pB1 + k0, &Bs[buf][2048 + tid * 8]);
    };

    const int fm = lane & 15, fq = lane >> 4;
    const int fqs = fq ^ ((fm >> 1) & 3);            // swizzled read chunk

    const int nt = K / 32;
    stage(0, 0);
    stage(1, 1);
    int b0 = 0, b1 = 1, b2 = 2;

    for (int t = 0; t < nt; ++t) {
        if (t + 2 < nt) stage(t + 2, b2);
        const int rem = nt - 1 - t;
        if (rem >= 2)      asm volatile("s_waitcnt vmcnt(8)" ::: "memory");
        else if (rem == 1) asm volatile("s_waitcnt vmcnt(4)" ::: "memory");
        else               asm volatile("s_waitcnt vmcnt(0)" ::: "memory");
        __builtin_amdgcn_s_barrier();
        asm volatile("" ::: "memory");
        bf16x8 af[4], bfr[4];
        #pragma unroll
        for (int i = 0; i < 4; i++)
            af[i] = *(const bf16x8*)&As[b0][(waveM + i * 16 + fm) * 32 + fqs * 8];
        #pragma unroll
        for (int j = 0; j < 4; j++)
            bfr[j] = *(const bf16x8*)&Bs[b0][(waveN + j * 16 + fm) * 32 + fqs * 8];
        #pragma unroll
        for (int i = 0; i < 4; i++)
            #pragma unroll
            for (int j = 0; j < 4; j++)
                acc[i][j] = __builtin_amdgcn_mfma_f32_16x16x32_bf16(af[i], bfr[j], acc[i][j], 0, 0, 0);
        asm volatile("" ::: "memory");
        __builtin_amdgcn_s_barrier();
        const int tmp = b0; b0 = b1; b1 = b2; b2 = tmp;
    }

    // C/D layout: col=lane&15, row=(lane>>4)*4+reg  [learn_hip m89/m91]
    #pragma unroll
    for (int j = 0; j < 4; j++) {
        const int col = f0 + waveN + j * 16 + fm;
        const float bcol = BIAS ? bias[col] : 0.f;
        float s = 0.f, s2 = 0.f;
        #pragma unroll
        for (int i = 0; i < 4; i++) {
            const int rb = m0 + waveM + i * 16 + fq * 4;
            #pragma unroll
            for (int r = 0; r < 4; r++) {
                const int row = rb + r;
                if (row < M) {
                    float v = acc[i][j][r] + bcol;
                    C[(size_t)row * F + col] = f2bf(v);
                    if (STATS) { s += v; s2 += v * v; }
                }
            }
        }
        if (STATS) {
            s += __shfl_xor(s, 16);
            s += __shfl_xor(s, 32);
            s2 += __shfl_xor(s2, 16);
            s2 += __shfl_xor(s2, 32);
            if (fq == 0) {
                atomicAdd(&colsum[col], s);
                atomicAdd(&colsq[col], s2);
            }
        }
    }
}

// ---------------- BN(2) + ReLU apply, finalize FOLDED ----------------

__global__ __launch_bounds__(256) void bnrelu_k(u16* __restrict__ H,
                                                const float* __restrict__ cs, const float* __restrict__ cq,
                                                const float* __restrict__ g, const float* __restrict__ be,
                                                int total) {
    __shared__ float lsc[512], lsh[512];
    const int t = threadIdx.x;
    for (int f = t; f < 512; f += 256) {
        float m = cs[f] * (1.f / NN);
        float v = cq[f] * (1.f / NN) - m * m;
        float s = rsqrtf(v + 1e-5f) * g[f];
        lsc[f] = s;
        lsh[f] = be[f] - m * s;
    }
    __syncthreads();

    int idx = blockIdx.x * 256 + t;
    int base = idx * 8;
    if (base >= total) return;
    uint4 p = *(const uint4*)(H + base);
    int col = base & 511;
    u32 w[4] = {p.x, p.y, p.z, p.w};
    u32 o[4];
    #pragma unroll
    for (int q = 0; q < 4; q++) {
        float x0 = fmaxf(fmaf(bflo(w[q]), lsc[col + 2 * q], lsh[col + 2 * q]), 0.f);
        float x1 = fmaxf(fmaf(bfhi(w[q]), lsc[col + 2 * q + 1], lsh[col + 2 * q + 1]), 0.f);
        o[q] = ((u32)f2bf(x1) << 16) | (u32)f2bf(x0);
    }
    uint4 po = {o[0], o[1], o[2], o[3]};
    *(uint4*)(H + base) = po;
}

// ---------------- launch ----------------

extern "C" void kernel_launch(void* const* d_in, const int* in_sizes, int n_in,
                              void* d_out, int out_size, void* d_ws, size_t ws_size,
                              hipStream_t stream) {
    const float* x   = (const float*)d_in[0];
    const int*   ei  = (const int*)d_in[1];
    const float* W1  = (const float*)d_in[2];
    const float* b1  = (const float*)d_in[3];
    const float* pg1 = (const float*)d_in[4];
    const float* pbe1= (const float*)d_in[5];
    const float* W2  = (const float*)d_in[6];
    const float* b2  = (const float*)d_in[7];
    const float* pg2 = (const float*)d_in[8];
    const float* pbe2= (const float*)d_in[9];
    const float* W3  = (const float*)d_in[10];
    const float* b3  = (const float*)d_in[11];
    float* out = (float*)d_out;

    char* ws = (char*)d_ws;
    size_t off = 0;
    auto alloc = [&](size_t bytes) -> char* {
        char* p = ws + off;
        off += (bytes + 255) & ~(size_t)255;
        return p;
    };
    float* dinv  = (float*)alloc(NN * 4);
    int*   deg   = (int*)alloc(NN * 4);       // deg + stats adjacent -> one memset
    float* stats = (float*)alloc(4 * 512 * 4);
    float* cs1 = stats, *cq1 = stats + 512, *cs2 = stats + 1024, *cq2 = stats + 1536;
    int*   rs    = (int*)alloc(NN * 4);
    int*   cur   = (int*)alloc(NN * 4);
    int*   bsum  = (int*)alloc(256 * 4);
    int*   csr   = (int*)alloc(NE * 4);
    u16*   W1t   = (u16*)alloc((size_t)512 * 256 * 2);
    u16*   W2t   = (u16*)alloc((size_t)512 * 512 * 2);
    u16*   W3t   = (u16*)alloc((size_t)256 * 512 * 2);
    u16*   HB    = (u16*)alloc((size_t)NN * 512 * 2);   // 51.2 MB
    u16*   G3    = (u16*)alloc((size_t)NN * 256 * 2);   // 25.6 MB; doubles as XB (x cast to bf16)

    u16* XB = G3;            // bf16 x — lifetime ends before gemm3 writes G3
    u16* A1 = (u16*)d_out;   // bf16 scratch [N,256] in d_out
    u16* A2 = (u16*)d_out;   // bf16 scratch [N,512] in d_out

    const int* srcp = ei;
    const int* dstp = ei + NE;

    // deg (200192B aligned) + stats (8192B) contiguous -> single memset
    const size_t degAligned = ((size_t)NN * 4 + 255) & ~(size_t)255;
    hipMemsetAsync(deg, 0, degAligned + 4 * 512 * 4, stream);

    const int nbN = (NN + 255) / 256;
    count_k<<<(NE + 255) / 256, 256, 0, stream>>>(dstp, deg, NE);
    scan1_k<<<nbN, 256, 0, stream>>>(deg, dinv, bsum, NN);
    scan2_k<<<1, 256, 0, stream>>>(bsum, nbN);
    scan3_k<<<nbN, 256, 0, stream>>>(deg, bsum, rs, cur, NN);
    fill_k<<<(NE + 255) / 256, 256, 0, stream>>>(srcp, dstp, cur, csr, NE);

    transpose_all_k<<<512, 256, 0, stream>>>(W1, W1t, W2, W2t, W3, W3t);

    cast_k<<<NN * 256 / 8 / 256, 256, 0, stream>>>(x, XB, NN * 256);

    const int MT = (NN + 127) / 128;  // 391
    const int AGB = (NN + 3) / 4;     // wave-per-node agg blocks (4 waves/block)

    // Layer 1: A1 = Agg(XB) [bf16, d_out, edge-paired]; H1 = A1@W1 + b1 -> HB + stats
    aggp_k<0><<<AGB, 256, 0, stream>>>(XB, A1, nullptr, dinv, rs, deg, csr,
                                       nullptr, nullptr);
    gemm_k<true, true><<<dim3(4, MT), 256, 0, stream>>>(A1, W1t, b1, HB, cs1, cq1, NN, 256, 512);

    // Layer 2: A2 = Agg(relu(bn1(H1))) [bf16, d_out], BN finalize folded, two half-node
    // launches; H2 = A2@W2 + b2 -> HB + stats
    agg2_k<<<AGB / 2, 256, 0, stream>>>(HB, A2, dinv, rs, deg, csr, cs1, cq1, pg1, pbe1, 0);
    agg2_k<<<AGB / 2, 256, 0, stream>>>(HB, A2, dinv, rs, deg, csr, cs1, cq1, pg1, pbe1, NN / 2);
    gemm_k<true, true><<<dim3(4, MT), 256, 0, stream>>>(A2, W2t, b2, HB, cs2, cq2, NN, 512, 512);
    bnrelu_k<<<NN * 512 / 8 / 256, 256, 0, stream>>>(HB, cs2, cq2, pg2, pbe2, NN * 512);

    // Layer 3: G3 = H2@W3 [bf16, ws, overwrites XB]; out = Agg(G3) + b3 + x [f32, edge-paired]
    gemm_k<false, false><<<dim3(2, MT), 256, 0, stream>>>(HB, W3t, nullptr, G3, nullptr, nullptr, NN, 512, 256);
    aggp_k<2><<<AGB, 256, 0, stream>>>(G3, nullptr, out, dinv, rs, deg, csr,
                                       b3, x);
}

// Round 10
// 594.308 us; speedup vs baseline: 1.8365x; 1.1019x over previous
//
#include <hip/hip_runtime.h>
#include <hip/hip_bf16.h>

#define NN 50000
#define NE 800000

typedef unsigned short u16;
typedef unsigned int   u32;

typedef __attribute__((ext_vector_type(8))) __bf16 bf16x8;
typedef __attribute__((ext_vector_type(4))) float  f32x4;

__device__ __forceinline__ float bf2f(u16 x) {
    u32 u = ((u32)x) << 16;
    return __builtin_bit_cast(float, u);
}
__device__ __forceinline__ u16 f2bf(float f) {
    u32 u = __builtin_bit_cast(u32, f);
    u32 r = (u + 0x7FFFu + ((u >> 16) & 1u)) >> 16;
    return (u16)r;
}
__device__ __forceinline__ float bflo(u32 w) { return __builtin_bit_cast(float, w << 16); }
__device__ __forceinline__ float bfhi(u32 w) { return __builtin_bit_cast(float, w & 0xffff0000u); }

__device__ __forceinline__ int rl_i(int v, int j) {
    return __builtin_amdgcn_readlane(v, j);
}
__device__ __forceinline__ float rl_f(float v, int j) {
    return __builtin_bit_cast(float, __builtin_amdgcn_readlane(__builtin_bit_cast(int, v), j));
}

// async global -> LDS, 16B per lane (HW: wave-uniform LDS base + lane*16; global addr per-lane)
__device__ __forceinline__ void glds16(const u16* g, u16* l) {
    __builtin_amdgcn_global_load_lds((const __attribute__((address_space(1))) void*)g,
                                     (__attribute__((address_space(3))) void*)l, 16, 0, 0);
}

// ---------------- graph preprocessing ----------------

__global__ __launch_bounds__(256) void count_k(const int* __restrict__ dst, int* __restrict__ deg, int E) {
    int e = blockIdx.x * 256 + threadIdx.x;
    if (e < E) atomicAdd(&deg[dst[e]], 1);
}

// scan1 + dinv fused (deg is final here; dinv = rsqrt(deg+1))
__global__ __launch_bounds__(256) void scan1_k(const int* __restrict__ deg, float* __restrict__ dinv,
                                               int* __restrict__ bsum, int n) {
    __shared__ int sd[256];
    int i = blockIdx.x * 256 + threadIdx.x;
    int v = (i < n) ? deg[i] : 0;
    if (i < n) dinv[i] = rsqrtf((float)v + 1.0f);
    sd[threadIdx.x] = v;
    __syncthreads();
    for (int s = 128; s > 0; s >>= 1) {
        if (threadIdx.x < s) sd[threadIdx.x] += sd[threadIdx.x + s];
        __syncthreads();
    }
    if (threadIdx.x == 0) bsum[blockIdx.x] = sd[0];
}

__global__ __launch_bounds__(256) void scan2_k(int* __restrict__ bsum, int nb) {
    __shared__ int sd[256];
    int t = threadIdx.x;
    int v = (t < nb) ? bsum[t] : 0;
    sd[t] = v;
    __syncthreads();
    for (int off = 1; off < 256; off <<= 1) {
        int tv = (t >= off) ? sd[t - off] : 0;
        __syncthreads();
        sd[t] += tv;
        __syncthreads();
    }
    if (t < nb) bsum[t] = sd[t] - v;  // exclusive
}

__global__ __launch_bounds__(256) void scan3_k(const int* __restrict__ deg, const int* __restrict__ bofs,
                                               int* __restrict__ rs, int* __restrict__ cur, int n) {
    __shared__ int sd[256];
    int t = threadIdx.x;
    int i = blockIdx.x * 256 + t;
    int v = (i < n) ? deg[i] : 0;
    sd[t] = v;
    __syncthreads();
    for (int off = 1; off < 256; off <<= 1) {
        int tv = (t >= off) ? sd[t - off] : 0;
        __syncthreads();
        sd[t] += tv;
        __syncthreads();
    }
    int excl = sd[t] - v + bofs[blockIdx.x];
    if (i < n) { rs[i] = excl; cur[i] = excl; }
}

__global__ __launch_bounds__(256) void fill_k(const int* __restrict__ src, const int* __restrict__ dst,
                                              int* __restrict__ cur, int* __restrict__ csr, int E) {
    int e = blockIdx.x * 256 + threadIdx.x;
    if (e < E) {
        int d = dst[e];
        int pos = atomicAdd(&cur[d], 1);
        csr[pos] = src[e];
    }
}

// ---------------- x f32 -> bf16 cast ----------------

__global__ __launch_bounds__(256) void cast_k(const float* __restrict__ X, u16* __restrict__ Y, int total) {
    int idx = (blockIdx.x * 256 + threadIdx.x) * 8;
    if (idx >= total) return;
    float4 a = *(const float4*)(X + idx);
    float4 b = *(const float4*)(X + idx + 4);
    uint4 o;
    o.x = (u32)f2bf(a.x) | ((u32)f2bf(a.y) << 16);
    o.y = (u32)f2bf(a.z) | ((u32)f2bf(a.w) << 16);
    o.z = (u32)f2bf(b.x) | ((u32)f2bf(b.y) << 16);
    o.w = (u32)f2bf(b.z) | ((u32)f2bf(b.w) << 16);
    *(uint4*)(Y + idx) = o;
}

// ---------------- all three weight transposes in ONE launch ----------------
// W f32[K][F] -> Wt bf16[F][K]. 512 blocks: 128 (W1 8x16 tiles) + 256 (W2) + 128 (W3).

__global__ __launch_bounds__(256) void transpose_all_k(const float* __restrict__ W1, u16* __restrict__ W1t,
                                                       const float* __restrict__ W2, u16* __restrict__ W2t,
                                                       const float* __restrict__ W3, u16* __restrict__ W3t) {
    int b = blockIdx.x;
    const float* W; u16* Wt; int K, F, t;
    if (b < 128)      { W = W1; Wt = W1t; K = 256; F = 512; t = b; }
    else if (b < 384) { W = W2; Wt = W2t; K = 512; F = 512; t = b - 128; }
    else              { W = W3; Wt = W3t; K = 512; F = 256; t = b - 384; }
    const int kt = K / 32;
    const int k0 = (t % kt) * 32, f0 = (t / kt) * 32;
    __shared__ float tt[32][33];
    int tx = threadIdx.x & 31, ty = threadIdx.x >> 5;
    for (int r = ty; r < 32; r += 8) tt[r][tx] = W[(size_t)(k0 + r) * F + f0 + tx];
    __syncthreads();
    for (int r = ty; r < 32; r += 8) Wt[(size_t)(f0 + r) * K + k0 + tx] = f2bf(tt[tx][r]);
}

// ---------------- agg2: F=512, wave-per-node, BN-finalize FOLDED ----------------

__global__ __launch_bounds__(256) void agg2_k(const u16* __restrict__ X, u16* __restrict__ Y,
                                              const float* __restrict__ dinv, const int* __restrict__ rs,
                                              const int* __restrict__ dg, const int* __restrict__ csr,
                                              const float* __restrict__ cs, const float* __restrict__ cq,
                                              const float* __restrict__ g, const float* __restrict__ be,
                                              int base) {
    __shared__ float lsc[512], lsh[512];
    const int tid = threadIdx.x;
    for (int f = tid; f < 512; f += 256) {
        float m = cs[f] * (1.f / NN);
        float v = cq[f] * (1.f / NN) - m * m;
        float s = rsqrtf(v + 1e-5f) * g[f];
        lsc[f] = s;
        lsh[f] = be[f] - m * s;
    }
    __syncthreads();

    const int lane = tid & 63;
    const int i = __builtin_amdgcn_readfirstlane(base + blockIdx.x * 4 + (tid >> 6));
    if (i >= NN) return;
    const int start = rs[i], cnt = dg[i];
    const float di = dinv[i];

    float sc[8], sh[8];
    #pragma unroll
    for (int k = 0; k < 8; k++) {
        sc[k] = lsc[lane * 8 + k];
        sh[k] = lsh[lane * 8 + k];
    }

    float acc[8];
    #pragma unroll
    for (int k = 0; k < 8; k++) acc[k] = 0.f;

    auto gadd = [&](int row, float wgt) {
        const u16* p = X + (size_t)row * 512 + lane * 8;
        uint4 q = *(const uint4*)p;
        float v[8];
        v[0] = bflo(q.x); v[1] = bfhi(q.x);
        v[2] = bflo(q.y); v[3] = bfhi(q.y);
        v[4] = bflo(q.z); v[5] = bfhi(q.z);
        v[6] = bflo(q.w); v[7] = bfhi(q.w);
        #pragma unroll
        for (int k = 0; k < 8; k++) {
            float x = fmaxf(fmaf(v[k], sc[k], sh[k]), 0.f);
            acc[k] = fmaf(x, wgt, acc[k]);
        }
    };

    gadd(i, di);  // self-loop term

    for (int bse = 0; bse < cnt; bse += 64) {
        const int m = min(64, cnt - bse);
        int   sidx = 0;
        float sw   = 0.f;
        if (lane < m) {
            sidx = csr[start + bse + lane];
            sw   = dinv[sidx];
        }
        int j = 0;
        for (; j + 8 <= m; j += 8) {
            int   r[8];
            float w[8];
            #pragma unroll
            for (int q = 0; q < 8; q++) {
                r[q] = rl_i(sidx, j + q);
                w[q] = rl_f(sw, j + q);
            }
            #pragma unroll
            for (int q = 0; q < 8; q++) gadd(r[q], w[q]);
        }
        for (; j < m; j++) gadd(rl_i(sidx, j), rl_f(sw, j));
    }

    uint4 o;
    o.x = (u32)f2bf(acc[0] * di) | ((u32)f2bf(acc[1] * di) << 16);
    o.y = (u32)f2bf(acc[2] * di) | ((u32)f2bf(acc[3] * di) << 16);
    o.z = (u32)f2bf(acc[4] * di) | ((u32)f2bf(acc[5] * di) << 16);
    o.w = (u32)f2bf(acc[6] * di) | ((u32)f2bf(acc[7] * di) << 16);
    *(uint4*)(Y + (size_t)i * 512 + lane * 8) = o;
}

// ---------------- GCN aggregation, F=256, EDGE-PAIRED (round-5/6 proven) -------

template <int MODE>
__global__ __launch_bounds__(256) void aggp_k(const u16* __restrict__ X, u16* __restrict__ Y,
                                              float* __restrict__ Yf,
                                              const float* __restrict__ dinv, const int* __restrict__ rs,
                                              const int* __restrict__ dg, const int* __restrict__ csr,
                                              const float* __restrict__ b3, const float* __restrict__ xres) {
    const int tid  = threadIdx.x;
    const int lane = tid & 63;
    const int hf   = lane >> 5;   // edge-pair half 0/1
    const int fl   = lane & 31;   // feat block: covers feats fl*8 .. fl*8+7
    const int i = blockIdx.x * 4 + (tid >> 6);  // one wave per node
    if (i >= NN) return;
    const int start = rs[i], cnt = dg[i];
    const float di = dinv[i];

    float acc[8];
    #pragma unroll
    for (int k = 0; k < 8; k++) acc[k] = 0.f;

    auto gadd = [&](int row, float wgt) {
        uint4 q = *(const uint4*)(X + (size_t)row * 256 + fl * 8);
        float v[8];
        v[0] = bflo(q.x); v[1] = bfhi(q.x);
        v[2] = bflo(q.y); v[3] = bfhi(q.y);
        v[4] = bflo(q.z); v[5] = bfhi(q.z);
        v[6] = bflo(q.w); v[7] = bfhi(q.w);
        #pragma unroll
        for (int k = 0; k < 8; k++) acc[k] = fmaf(v[k], wgt, acc[k]);
    };

    // self-loop: lower half contributes di, upper half 0 (counted once after merge)
    gadd(i, hf ? 0.f : di);

    for (int bse = 0; bse < cnt; bse += 64) {
        const int m = min(64, cnt - bse);
        int   sidx = 0;
        float sw   = 0.f;   // lanes >= m keep (row 0, weight 0): zero contribution
        if (lane < m) {
            sidx = csr[start + bse + lane];
            sw   = dinv[sidx];
        }
        int j = 0;
        for (; j + 8 <= m; j += 8) {
            int   r0 = __shfl(sidx, j + 0 + hf), r1 = __shfl(sidx, j + 2 + hf);
            int   r2 = __shfl(sidx, j + 4 + hf), r3 = __shfl(sidx, j + 6 + hf);
            float w0 = __shfl(sw, j + 0 + hf), w1 = __shfl(sw, j + 2 + hf);
            float w2 = __shfl(sw, j + 4 + hf), w3 = __shfl(sw, j + 6 + hf);
            gadd(r0, w0);
            gadd(r1, w1);
            gadd(r2, w2);
            gadd(r3, w3);
        }
        for (; j < m; j += 2) {
            gadd(__shfl(sidx, j + hf), __shfl(sw, j + hf));
        }
    }

    // merge the two edge halves (fl preserved)
    #pragma unroll
    for (int k = 0; k < 8; k++) acc[k] += __shfl_xor(acc[k], 32);

    if (hf == 0) {
        if constexpr (MODE == 2) {
            const float* xr = xres + (size_t)i * 256 + fl * 8;
            float4 x0 = *(const float4*)xr;
            float4 x1 = *(const float4*)(xr + 4);
            float4 b0 = *(const float4*)(b3 + fl * 8);
            float4 b1 = *(const float4*)(b3 + fl * 8 + 4);
            float4 o0, o1;
            o0.x = acc[0] * di + b0.x + x0.x; o0.y = acc[1] * di + b0.y + x0.y;
            o0.z = acc[2] * di + b0.z + x0.z; o0.w = acc[3] * di + b0.w + x0.w;
            o1.x = acc[4] * di + b1.x + x1.x; o1.y = acc[5] * di + b1.y + x1.y;
            o1.z = acc[6] * di + b1.z + x1.z; o1.w = acc[7] * di + b1.w + x1.w;
            float* yp = Yf + (size_t)i * 256 + fl * 8;
            *(float4*)yp = o0;
            *(float4*)(yp + 4) = o1;
        } else {
            uint4 o;
            o.x = (u32)f2bf(acc[0] * di) | ((u32)f2bf(acc[1] * di) << 16);
            o.y = (u32)f2bf(acc[2] * di) | ((u32)f2bf(acc[3] * di) << 16);
            o.z = (u32)f2bf(acc[4] * di) | ((u32)f2bf(acc[5] * di) << 16);
            o.w = (u32)f2bf(acc[6] * di) | ((u32)f2bf(acc[7] * di) << 16);
            *(uint4*)(Y + (size_t)i * 256 + fl * 8) = o;
        }
    }
}

// ---------------- bf16 MFMA GEMM: C[M][F] = A[M][K] @ Wt[F][K]^T (+bias, +col stats) ----
// 128x128 tile, BK=32, 4 waves each 64x64 (4x4 of 16x16x32 MFMA). C bf16 out.
// glds width-16, unpadded LDS + XOR bank-swizzle (r8); triple-buffered counted-vmcnt
// K-loop (r9); grid (F-tiles, M-tiles).
//
// ROUND 10: LDS-COALESCED EPILOGUE. r9 PMC: FETCH 101.5MB = A + ~C (write-allocate
// RMW from 2B scattered stores), WRITE 117MB = 2.3x C. Fix: after the K-loop, alias
// the dead staging LDS as a [64][132] f32 tile; two passes (frag i {0,1} / {2,3}):
// waves write bias-added acc to LDS, sync, then 256 threads store full 16B uint4
// chunks (256B contiguous per row -> no write-allocate). Stats stay register-based.

template <bool STATS, bool BIAS>
__global__ __launch_bounds__(256) void gemm_k(const u16* __restrict__ A, const u16* __restrict__ Wt,
                                              const float* __restrict__ bias, u16* __restrict__ C,
                                              float* __restrict__ colsum, float* __restrict__ colsq,
                                              int M, int K, int F) {
    __shared__ u16 smem[2 * 3 * 4096];   // 49152 B: As[3][4096] | Bs[3][4096]
    u16* Asb = smem;
    u16* Bsb = smem + 3 * 4096;
    const int f0 = blockIdx.x * 128, m0 = blockIdx.y * 128;   // x = F-tile (fast-varying)
    const int tid = threadIdx.x;
    const int lane = tid & 63, wave = tid >> 6;
    const int waveM = (wave >> 1) * 64, waveN = (wave & 1) * 64;
    const int lrow = tid >> 2;
    const int lch  = (tid & 3) ^ ((tid >> 3) & 3);   // pre-swizzled global chunk

    f32x4 acc[4][4];
    const f32x4 fz = {0.f, 0.f, 0.f, 0.f};
    #pragma unroll
    for (int i = 0; i < 4; i++)
        #pragma unroll
        for (int j = 0; j < 4; j++) acc[i][j] = fz;

    const int rA0 = m0 + lrow, rA1 = m0 + 64 + lrow;
    const int cA0 = (rA0 < M) ? rA0 : (M - 1);
    const int cA1 = (rA1 < M) ? rA1 : (M - 1);
    const u16* pA0 = A + (size_t)cA0 * K + lch * 8;
    const u16* pA1 = A + (size_t)cA1 * K + lch * 8;
    const u16* pB0 = Wt + (size_t)(f0 + lrow) * K + lch * 8;
    const u16* pB1 = Wt + (size_t)(f0 + 64 + lrow) * K + lch * 8;

    auto stage = [&](int tile, int buf) {
        const int k0 = tile * 32;
        glds16(pA0 + k0, &Asb[buf * 4096 + tid * 8]);
        glds16(pA1 + k0, &Asb[buf * 4096 + 2048 + tid * 8]);
        glds16(pB0 + k0, &Bsb[buf * 4096 + tid * 8]);
        glds16(pB1 + k0, &Bsb[buf * 4096 + 2048 + tid * 8]);
    };

    const int fm = lane & 15, fq = lane >> 4;
    const int fqs = fq ^ ((fm >> 1) & 3);            // swizzled read chunk

    const int nt = K / 32;
    stage(0, 0);
    stage(1, 1);
    int b0 = 0, b1 = 1, b2 = 2;

    for (int t = 0; t < nt; ++t) {
        if (t + 2 < nt) stage(t + 2, b2);
        const int rem = nt - 1 - t;
        if (rem >= 2)      asm volatile("s_waitcnt vmcnt(8)" ::: "memory");
        else if (rem == 1) asm volatile("s_waitcnt vmcnt(4)" ::: "memory");
        else               asm volatile("s_waitcnt vmcnt(0)" ::: "memory");
        __builtin_amdgcn_s_barrier();
        asm volatile("" ::: "memory");
        bf16x8 af[4], bfr[4];
        #pragma unroll
        for (int i = 0; i < 4; i++)
            af[i] = *(const bf16x8*)&Asb[b0 * 4096 + (waveM + i * 16 + fm) * 32 + fqs * 8];
        #pragma unroll
        for (int j = 0; j < 4; j++)
            bfr[j] = *(const bf16x8*)&Bsb[b0 * 4096 + (waveN + j * 16 + fm) * 32 + fqs * 8];
        #pragma unroll
        for (int i = 0; i < 4; i++)
            #pragma unroll
            for (int j = 0; j < 4; j++)
                acc[i][j] = __builtin_amdgcn_mfma_f32_16x16x32_bf16(af[i], bfr[j], acc[i][j], 0, 0, 0);
        asm volatile("" ::: "memory");
        __builtin_amdgcn_s_barrier();
        const int tmp = b0; b0 = b1; b1 = b2; b2 = tmp;
    }

    // ---- stats (register path; C/D layout col=lane&15, row=(lane>>4)*4+reg) ----
    float bcolv[4];
    #pragma unroll
    for (int j = 0; j < 4; j++)
        bcolv[j] = BIAS ? bias[f0 + waveN + j * 16 + fm] : 0.f;

    if (STATS) {
        #pragma unroll
        for (int j = 0; j < 4; j++) {
            const int col = f0 + waveN + j * 16 + fm;
            float s = 0.f, s2 = 0.f;
            #pragma unroll
            for (int i = 0; i < 4; i++) {
                const int rb = m0 + waveM + i * 16 + fq * 4;
                #pragma unroll
                for (int r = 0; r < 4; r++) {
                    if (rb + r < M) {
                        float v = acc[i][j][r] + bcolv[j];
                        s += v; s2 += v * v;
                    }
                }
            }
            s += __shfl_xor(s, 16);
            s += __shfl_xor(s, 32);
            s2 += __shfl_xor(s2, 16);
            s2 += __shfl_xor(s2, 32);
            if (fq == 0) {
                atomicAdd(&colsum[col], s);
                atomicAdd(&colsq[col], s2);
            }
        }
    }

    // ---- LDS-coalesced C store: alias staging LDS as [64][132] f32 ----
    float* ct = (float*)smem;
    const int CPAD = 132;
    #pragma unroll
    for (int p = 0; p < 2; ++p) {
        __syncthreads();   // staging reads done (p=0) / previous pass reads done (p=1)
        #pragma unroll
        for (int ii = 0; ii < 2; ++ii) {
            const int i = 2 * p + ii;
            #pragma unroll
            for (int j = 0; j < 4; j++) {
                const int lc = waveN + j * 16 + fm;
                #pragma unroll
                for (int r = 0; r < 4; r++) {
                    const int lr = (waveM >> 1) + ii * 16 + fq * 4 + r;
                    ct[lr * CPAD + lc] = acc[i][j][r] + bcolv[j];
                }
            }
        }
        __syncthreads();
        for (int c = tid; c < 1024; c += 256) {
            const int lr = c >> 4;
            const int c8 = (c & 15) * 8;
            const int grow = m0 + ((lr & 32) << 1) + p * 32 + (lr & 31);
            if (grow < M) {
                const float* rp = ct + lr * CPAD + c8;
                uint4 o;
                o.x = (u32)f2bf(rp[0]) | ((u32)f2bf(rp[1]) << 16);
                o.y = (u32)f2bf(rp[2]) | ((u32)f2bf(rp[3]) << 16);
                o.z = (u32)f2bf(rp[4]) | ((u32)f2bf(rp[5]) << 16);
                o.w = (u32)f2bf(rp[6]) | ((u32)f2bf(rp[7]) << 16);
                *(uint4*)(C + (size_t)grow * F + f0 + c8) = o;
            }
        }
    }
}

// ---------------- BN(2) + ReLU apply, finalize FOLDED ----------------

__global__ __launch_bounds__(256) void bnrelu_k(u16* __restrict__ H,
                                                const float* __restrict__ cs, const float* __restrict__ cq,
                                                const float* __restrict__ g, const float* __restrict__ be,
                                                int total) {
    __shared__ float lsc[512], lsh[512];
    const int t = threadIdx.x;
    for (int f = t; f < 512; f += 256) {
        float m = cs[f] * (1.f / NN);
        float v = cq[f] * (1.f / NN) - m * m;
        float s = rsqrtf(v + 1e-5f) * g[f];
        lsc[f] = s;
        lsh[f] = be[f] - m * s;
    }
    __syncthreads();

    int idx = blockIdx.x * 256 + t;
    int base = idx * 8;
    if (base >= total) return;
    uint4 p = *(const uint4*)(H + base);
    int col = base & 511;
    u32 w[4] = {p.x, p.y, p.z, p.w};
    u32 o[4];
    #pragma unroll
    for (int q = 0; q < 4; q++) {
        float x0 = fmaxf(fmaf(bflo(w[q]), lsc[col + 2 * q], lsh[col + 2 * q]), 0.f);
        float x1 = fmaxf(fmaf(bfhi(w[q]), lsc[col + 2 * q + 1], lsh[col + 2 * q + 1]), 0.f);
        o[q] = ((u32)f2bf(x1) << 16) | (u32)f2bf(x0);
    }
    uint4 po = {o[0], o[1], o[2], o[3]};
    *(uint4*)(H + base) = po;
}

// ---------------- launch ----------------

extern "C" void kernel_launch(void* const* d_in, const int* in_sizes, int n_in,
                              void* d_out, int out_size, void* d_ws, size_t ws_size,
                              hipStream_t stream) {
    const float* x   = (const float*)d_in[0];
    const int*   ei  = (const int*)d_in[1];
    const float* W1  = (const float*)d_in[2];
    const float* b1  = (const float*)d_in[3];
    const float* pg1 = (const float*)d_in[4];
    const float* pbe1= (const float*)d_in[5];
    const float* W2  = (const float*)d_in[6];
    const float* b2  = (const float*)d_in[7];
    const float* pg2 = (const float*)d_in[8];
    const float* pbe2= (const float*)d_in[9];
    const float* W3  = (const float*)d_in[10];
    const float* b3  = (const float*)d_in[11];
    float* out = (float*)d_out;

    char* ws = (char*)d_ws;
    size_t off = 0;
    auto alloc = [&](size_t bytes) -> char* {
        char* p = ws + off;
        off += (bytes + 255) & ~(size_t)255;
        return p;
    };
    float* dinv  = (float*)alloc(NN * 4);
    int*   deg   = (int*)alloc(NN * 4);       // deg + stats adjacent -> one memset
    float* stats = (float*)alloc(4 * 512 * 4);
    float* cs1 = stats, *cq1 = stats + 512, *cs2 = stats + 1024, *cq2 = stats + 1536;
    int*   rs    = (int*)alloc(NN * 4);
    int*   cur   = (int*)alloc(NN * 4);
    int*   bsum  = (int*)alloc(256 * 4);
    int*   csr   = (int*)alloc(NE * 4);
    u16*   W1t   = (u16*)alloc((size_t)512 * 256 * 2);
    u16*   W2t   = (u16*)alloc((size_t)512 * 512 * 2);
    u16*   W3t   = (u16*)alloc((size_t)256 * 512 * 2);
    u16*   HB    = (u16*)alloc((size_t)NN * 512 * 2);   // 51.2 MB
    u16*   G3    = (u16*)alloc((size_t)NN * 256 * 2);   // 25.6 MB; doubles as XB (x cast to bf16)

    u16* XB = G3;            // bf16 x — lifetime ends before gemm3 writes G3
    u16* A1 = (u16*)d_out;   // bf16 scratch [N,256] in d_out
    u16* A2 = (u16*)d_out;   // bf16 scratch [N,512] in d_out

    const int* srcp = ei;
    const int* dstp = ei + NE;

    // deg (200192B aligned) + stats (8192B) contiguous -> single memset
    const size_t degAligned = ((size_t)NN * 4 + 255) & ~(size_t)255;
    hipMemsetAsync(deg, 0, degAligned + 4 * 512 * 4, stream);

    const int nbN = (NN + 255) / 256;
    count_k<<<(NE + 255) / 256, 256, 0, stream>>>(dstp, deg, NE);
    scan1_k<<<nbN, 256, 0, stream>>>(deg, dinv, bsum, NN);
    scan2_k<<<1, 256, 0, stream>>>(bsum, nbN);
    scan3_k<<<nbN, 256, 0, stream>>>(deg, bsum, rs, cur, NN);
    fill_k<<<(NE + 255) / 256, 256, 0, stream>>>(srcp, dstp, cur, csr, NE);

    transpose_all_k<<<512, 256, 0, stream>>>(W1, W1t, W2, W2t, W3, W3t);

    cast_k<<<NN * 256 / 8 / 256, 256, 0, stream>>>(x, XB, NN * 256);

    const int MT = (NN + 127) / 128;  // 391
    const int AGB = (NN + 3) / 4;     // wave-per-node agg blocks (4 waves/block)

    // Layer 1: A1 = Agg(XB) [bf16, d_out, edge-paired]; H1 = A1@W1 + b1 -> HB + stats
    aggp_k<0><<<AGB, 256, 0, stream>>>(XB, A1, nullptr, dinv, rs, deg, csr,
                                       nullptr, nullptr);
    gemm_k<true, true><<<dim3(4, MT), 256, 0, stream>>>(A1, W1t, b1, HB, cs1, cq1, NN, 256, 512);

    // Layer 2: A2 = Agg(relu(bn1(H1))) [bf16, d_out], BN finalize folded, two half-node
    // launches; H2 = A2@W2 + b2 -> HB + stats
    agg2_k<<<AGB / 2, 256, 0, stream>>>(HB, A2, dinv, rs, deg, csr, cs1, cq1, pg1, pbe1, 0);
    agg2_k<<<AGB / 2, 256, 0, stream>>>(HB, A2, dinv, rs, deg, csr, cs1, cq1, pg1, pbe1, NN / 2);
    gemm_k<true, true><<<dim3(4, MT), 256, 0, stream>>>(A2, W2t, b2, HB, cs2, cq2, NN, 512, 512);
    bnrelu_k<<<NN * 512 / 8 / 256, 256, 0, stream>>>(HB, cs2, cq2, pg2, pbe2, NN * 512);

    // Layer 3: G3 = H2@W3 [bf16, ws, overwrites XB]; out = Agg(G3) + b3 + x [f32, edge-paired]
    gemm_k<false, false><<<dim3(2, MT), 256, 0, stream>>>(HB, W3t, nullptr, G3, nullptr, nullptr, NN, 512, 256);
    aggp_k<2><<<AGB, 256, 0, stream>>>(G3, nullptr, out, dinv, rs, deg, csr,
                                       b3, x);
}